// Round 13
// baseline (198.363 us; speedup 1.0000x reference)
//
#include <hip/hip_runtime.h>
#include <hip/hip_bf16.h>

#define BATCH 16
#define TLEN 2048
#define CDIM 1024
#define HDIM 128

typedef __attribute__((ext_vector_type(8))) short bf16x8;
typedef __attribute__((ext_vector_type(4))) float f32x4;
typedef __attribute__((ext_vector_type(16))) float f32x16;
typedef __attribute__((ext_vector_type(4))) unsigned short u16x4;
typedef __attribute__((ext_vector_type(8))) unsigned short u16x8;

static __device__ __forceinline__ unsigned short f2bf(float f) {
    __hip_bfloat16 h = __float2bfloat16(f);
    return *(unsigned short*)&h;
}
static __device__ __forceinline__ unsigned pkbf(float a, float b) {
    return (unsigned)f2bf(a) | ((unsigned)f2bf(b) << 16);
}
// partials per (b,qc) prefix:  sum_{j<qc} (j/2 + 1)
static __device__ __forceinline__ int part_offs(int qc) {
    return qc + ((qc * qc - 2 * qc + (qc & 1)) >> 2);
}

// ---------------------------------------------------------------------------
// Prep: pack Wq|Wk|Wv into transposed bf16  wtb[(which*128+n)*1024 + k].
// ---------------------------------------------------------------------------
__global__ __launch_bounds__(256) void pack_w(
    const float* __restrict__ Wq, const float* __restrict__ Wk,
    const float* __restrict__ Wv, unsigned short* __restrict__ wtb)
{
    const int which = blockIdx.y;
    const float* W = (which == 0) ? Wq : (which == 1) ? Wk : Wv;
    const int n = blockIdx.x >> 2;
    const int k = (blockIdx.x & 3) * 256 + threadIdx.x;
    wtb[((size_t)which * 128 + n) * 1024 + k] = f2bf(W[(size_t)k * 128 + n]);
}

// ---------------------------------------------------------------------------
// Kernel 1: FUSED QKV projection — ALL-REGISTER, no LDS, no barriers.
// Grid 512 x 256 threads; each of 4 waves owns a 64x96 output tile
// (rows m0..m0+63, cols wid*96..+96 of q|k|v).  Per K-step (BK=32):
// A: 8 x dwordx4 fp32 from x (cvt to bf16 in-reg), B: 6 x 16B bf16 from
// wtb (L2-resident).  Explicit even/odd register double-buffer (static
// names, rule-20 safe) lets the compiler overlap step t+1 loads with
// step t MFMAs; all waitcnts compiler-managed.
// ---------------------------------------------------------------------------
__global__ __launch_bounds__(256, 2) void qkv_fused(
    const float* __restrict__ x, const unsigned short* __restrict__ wtb,
    unsigned short* __restrict__ qb, unsigned short* __restrict__ kb,
    unsigned short* __restrict__ vtb)
{
    const int tid  = threadIdx.x;
    const int lane = tid & 63, wid = tid >> 6;    // 4 waves = 4 n-slices
    const int c = lane & 15, g = lane >> 4;
    const int m0 = blockIdx.x * 64;

    const float* xp = x + (size_t)(m0 + c) * CDIM + g * 8;
    const unsigned short* wp = wtb + (size_t)(wid * 96 + c) * 1024 + g * 8;

    f32x4 acc[4][6];
#pragma unroll
    for (int i = 0; i < 4; ++i)
#pragma unroll
        for (int j = 0; j < 6; ++j) acc[i][j] = (f32x4){0.f, 0.f, 0.f, 0.f};

    float4 Ae[8], Ao[8];
    bf16x8 Be[6], Bo[6];

#define LOADK(A_, B_, k0_)                                                   \
    { _Pragma("unroll")                                                      \
      for (int mf_ = 0; mf_ < 4; ++mf_) {                                    \
          const float* s_ = xp + (size_t)(mf_ * 16) * CDIM + (k0_);          \
          A_[2 * mf_]     = *(const float4*)s_;                              \
          A_[2 * mf_ + 1] = *(const float4*)(s_ + 4);                        \
      }                                                                      \
      _Pragma("unroll")                                                      \
      for (int nf_ = 0; nf_ < 6; ++nf_)                                      \
          B_[nf_] = *(const bf16x8*)(wp + (size_t)(nf_ * 16) * 1024 + (k0_)); }

#define COMPUTE(A_, B_)                                                      \
    { bf16x8 af_[4];                                                         \
      _Pragma("unroll")                                                      \
      for (int mf_ = 0; mf_ < 4; ++mf_) {                                    \
          const float4 lo_ = A_[2 * mf_], hi_ = A_[2 * mf_ + 1];             \
          bf16x8 t_;                                                         \
          t_[0] = f2bf(lo_.x); t_[1] = f2bf(lo_.y);                          \
          t_[2] = f2bf(lo_.z); t_[3] = f2bf(lo_.w);                          \
          t_[4] = f2bf(hi_.x); t_[5] = f2bf(hi_.y);                          \
          t_[6] = f2bf(hi_.z); t_[7] = f2bf(hi_.w);                          \
          af_[mf_] = t_;                                                     \
      }                                                                      \
      _Pragma("unroll")                                                      \
      for (int mf_ = 0; mf_ < 4; ++mf_)                                      \
          _Pragma("unroll")                                                  \
          for (int nf_ = 0; nf_ < 6; ++nf_)                                  \
              acc[mf_][nf_] = __builtin_amdgcn_mfma_f32_16x16x32_bf16(       \
                  af_[mf_], B_[nf_], acc[mf_][nf_], 0, 0, 0); }

    LOADK(Ae, Be, 0);
#pragma unroll 1
    for (int kt = 0; kt < 32; kt += 2) {
        LOADK(Ao, Bo, (kt + 1) * 32);
        COMPUTE(Ae, Be);
        if (kt + 2 < 32) LOADK(Ae, Be, (kt + 2) * 32);
        COMPUTE(Ao, Bo);
    }

    // ---- epilogue: per-fragment route to q (scaled) / k / v^T ----
#pragma unroll
    for (int mf = 0; mf < 4; ++mf) {
#pragma unroll
        for (int nf = 0; nf < 6; ++nf) {
            const int col0 = wid * 96 + nf * 16;
            const int nt = col0 >> 7;
            const int nc = (col0 & 127) + c;
            const int m = m0 + mf * 16 + g * 4;
            if (nt == 0) {
#pragma unroll
                for (int r = 0; r < 4; ++r)
                    qb[(size_t)(m + r) * HDIM + nc] = f2bf(acc[mf][nf][r] * 0.03125f);
            } else if (nt == 1) {
#pragma unroll
                for (int r = 0; r < 4; ++r)
                    kb[(size_t)(m + r) * HDIM + nc] = f2bf(acc[mf][nf][r]);
            } else {
                const int b = m >> 11, tl = m & (TLEN - 1);
                u16x4 o;
                o[0] = f2bf(acc[mf][nf][0]); o[1] = f2bf(acc[mf][nf][1]);
                o[2] = f2bf(acc[mf][nf][2]); o[3] = f2bf(acc[mf][nf][3]);
                *(u16x4*)(vtb + ((size_t)b * HDIM + nc) * TLEN + tl) = o;
            }
        }
    }
#undef LOADK
#undef COMPUTE
}

// ---------------------------------------------------------------------------
// Kernel 2a: flash-attention partials, 32x32 swapped-operand structure
// (unchanged — passed since round 7).
// ---------------------------------------------------------------------------
__global__ __launch_bounds__(256, 2) void attn_partial(
    const short* __restrict__ qb, const short* __restrict__ kb,
    const short* __restrict__ vtb,
    unsigned short* __restrict__ Opart, float* __restrict__ mpart,
    float* __restrict__ lpart)
{
    const int kc = blockIdx.x;
    const int qc = blockIdx.y;
    const int b  = blockIdx.z;
    if (kc > (qc >> 1)) return;
    const int kv_base = kc * 256;
    const int qrel = qc * 128 - kv_base;
    int NT = ((qrel + 127) >> 6) + 1; if (NT > 4) NT = 4;

    __shared__ unsigned short Ks[2][64 * 128];
    __shared__ unsigned short Vs[2][128 * 64];

    const int tid  = threadIdx.x;
    const int wid  = tid >> 6;
    const int lane = tid & 63;
    const int c5 = lane & 31, hi = lane >> 5;
    const int q0w = qc * 128 + wid * 32;
    const int qg  = q0w + c5;
    const int pidx = b * 72 + part_offs(qc) + kc;

    const short* Kb  = kb  + (size_t)b * TLEN * HDIM;
    const short* Vtb = vtb + (size_t)b * HDIM * TLEN;

    bf16x8 qf[8];
#pragma unroll
    for (int ks = 0; ks < 8; ++ks)
        qf[ks] = *(const bf16x8*)(qb + ((size_t)b * TLEN + qg) * HDIM + ks * 16 + hi * 8);

    bf16x8 kst[4], vst[4];

#define GLOAD(kv0_)                                                          \
    {                                                                        \
        _Pragma("unroll")                                                    \
        for (int it = 0; it < 4; ++it) {                                     \
            const int o = tid * 16 + it * 4096;                              \
            const int kr = o >> 8, kcb = o & 0xF0;                           \
            kst[it] = *(const bf16x8*)((const char*)Kb +                     \
                        (size_t)((kv0_) + kr) * 256 + kcb);                  \
            const int vr = o >> 7, vcb = o & 0x70;                           \
            vst[it] = *(const bf16x8*)((const char*)Vtb +                    \
                        (size_t)vr * (TLEN * 2) + (size_t)(kv0_) * 2 + vcb); \
        }                                                                    \
    }
#define SSTORE(bi_)                                                          \
    {                                                                        \
        _Pragma("unroll")                                                    \
        for (int it = 0; it < 4; ++it) {                                     \
            const int o = tid * 16 + it * 4096;                              \
            const int kr = o >> 8, kcb = o & 0xF0;                           \
            *(bf16x8*)((char*)Ks[bi_] + kr * 256 + (kcb ^ ((kr & 7) << 4))) = kst[it]; \
            const int vr = o >> 7, vcb = o & 0x70;                           \
            *(bf16x8*)((char*)Vs[bi_] + vr * 128 + (vcb ^ ((vr & 7) << 4))) = vst[it]; \
        }                                                                    \
    }

    GLOAD(kv_base);
    SSTORE(0);
    __syncthreads();

    f32x16 oacc[4];
#pragma unroll
    for (int i = 0; i < 4; ++i)
#pragma unroll
        for (int r = 0; r < 16; ++r) oacc[i][r] = 0.f;
    float m_r = -1e30f;
    float l_r = 0.f;

#pragma unroll 1
    for (int t = 0; t < NT; ++t) {
        const int bi = t & 1;
        if (t + 1 < NT) GLOAD(kv_base + 64 * (t + 1));

        const int kv0 = kv_base + 64 * t;
        if (kv0 <= q0w + 31) {
            f32x16 s0, s1;
#pragma unroll
            for (int r = 0; r < 16; ++r) { s0[r] = 0.f; s1[r] = 0.f; }
            __builtin_amdgcn_s_setprio(1);
#pragma unroll
            for (int ks = 0; ks < 8; ++ks) {
                const int col = ks * 32 + hi * 16;
                const int off0 = c5 * 256 + (col ^ ((c5 & 7) << 4));
                const int off1 = (32 + c5) * 256 + (col ^ ((c5 & 7) << 4));
                bf16x8 a0 = *(const bf16x8*)((char*)Ks[bi] + off0);
                bf16x8 a1 = *(const bf16x8*)((char*)Ks[bi] + off1);
                s0 = __builtin_amdgcn_mfma_f32_32x32x16_bf16(a0, qf[ks], s0, 0, 0, 0);
                s1 = __builtin_amdgcn_mfma_f32_32x32x16_bf16(a1, qf[ks], s1, 0, 0, 0);
            }
            __builtin_amdgcn_s_setprio(0);

            if (kv0 + 63 > q0w) {
#pragma unroll
                for (int r = 0; r < 16; ++r) {
                    const int key0 = kv0 + (r & 3) + 8 * (r >> 2) + 4 * hi;
                    if (key0 > qg)      s0[r] = -INFINITY;
                    if (key0 + 32 > qg) s1[r] = -INFINITY;
                }
            }

            float t8[8];
#pragma unroll
            for (int i = 0; i < 8; ++i)
                t8[i] = fmaxf(fmaxf(s0[2*i], s0[2*i+1]), fmaxf(s1[2*i], s1[2*i+1]));
            float smax = fmaxf(fmaxf(fmaxf(t8[0], t8[1]), fmaxf(t8[2], t8[3])),
                               fmaxf(fmaxf(t8[4], t8[5]), fmaxf(t8[6], t8[7])));
            smax = fmaxf(smax, __shfl_xor(smax, 32));

            const bool defer = __all(smax - m_r <= 8.0f);   // T13
            const float mnew = defer ? m_r : fmaxf(m_r, smax);
            if (!defer) {
                const float alpha = __expf(m_r - mnew);
                l_r *= alpha;
#pragma unroll
                for (int hb = 0; hb < 4; ++hb) oacc[hb] = oacc[hb] * alpha;
            }
            m_r = mnew;

#pragma unroll
            for (int r = 0; r < 16; ++r) {
                s0[r] = __expf(s0[r] - mnew);
                s1[r] = __expf(s1[r] - mnew);
            }
            float a8[8];
#pragma unroll
            for (int i = 0; i < 8; ++i)
                a8[i] = (s0[2*i] + s0[2*i+1]) + (s1[2*i] + s1[2*i+1]);
            float psum = ((a8[0] + a8[1]) + (a8[2] + a8[3])) +
                         ((a8[4] + a8[5]) + (a8[6] + a8[7]));
            psum += __shfl_xor(psum, 32);
            l_r += psum;

            bf16x8 pa[4];
#pragma unroll
            for (int kb2 = 0; kb2 < 2; ++kb2) {
#pragma unroll
                for (int par = 0; par < 2; ++par) {
                    const int e = par * 8;
                    float v0, v1, v2, v3, v4, v5, v6, v7;
                    if (kb2 == 0) {
                        v0=s0[e+0]; v1=s0[e+1]; v2=s0[e+2]; v3=s0[e+3];
                        v4=s0[e+4]; v5=s0[e+5]; v6=s0[e+6]; v7=s0[e+7];
                    } else {
                        v0=s1[e+0]; v1=s1[e+1]; v2=s1[e+2]; v3=s1[e+3];
                        v4=s1[e+4]; v5=s1[e+5]; v6=s1[e+6]; v7=s1[e+7];
                    }
                    const unsigned w0 = pkbf(v0, v1), w1 = pkbf(v2, v3);
                    const unsigned w2 = pkbf(v4, v5), w3 = pkbf(v6, v7);
                    const unsigned X0 = hi ? w0 : w2;
                    const unsigned X1 = hi ? w1 : w3;
                    const unsigned R0 = (unsigned)__shfl_xor((int)X0, 32);
                    const unsigned R1 = (unsigned)__shfl_xor((int)X1, 32);
                    union { unsigned w[4]; bf16x8 v; } uu;
                    uu.w[0] = hi ? R0 : w0;  uu.w[1] = hi ? R1 : w1;
                    uu.w[2] = hi ? w2 : R0;  uu.w[3] = hi ? w3 : R1;
                    pa[kb2 * 2 + par] = uu.v;
                }
            }

            __builtin_amdgcn_s_setprio(1);
#pragma unroll
            for (int hb = 0; hb < 4; ++hb) {
                const int row = hb * 32 + c5;
#pragma unroll
                for (int ks = 0; ks < 4; ++ks) {
                    const int off = row * 128 + ((ks * 32 + hi * 16) ^ ((row & 7) << 4));
                    bf16x8 va = *(const bf16x8*)((char*)Vs[bi] + off);
                    oacc[hb] = __builtin_amdgcn_mfma_f32_32x32x16_bf16(va, pa[ks], oacc[hb], 0, 0, 0);
                }
            }
            __builtin_amdgcn_s_setprio(0);
        }

        if (t + 1 < NT) {
            SSTORE(bi ^ 1);
            __syncthreads();
        }
    }

    // ---- epilogue: transpose O via LDS, store partials bf16 ----
    __syncthreads();
    char* sl = (char*)Ks + wid * 8192;
#pragma unroll
    for (int hb = 0; hb < 4; ++hb)
#pragma unroll
        for (int rq = 0; rq < 4; ++rq) {
            u16x4 o4;
            o4[0] = f2bf(oacc[hb][rq * 4 + 0]);
            o4[1] = f2bf(oacc[hb][rq * 4 + 1]);
            o4[2] = f2bf(oacc[hb][rq * 4 + 2]);
            o4[3] = f2bf(oacc[hb][rq * 4 + 3]);
            const int off = c5 * 256 + ((hb * 64 + rq * 16 + hi * 8) ^ ((c5 & 7) << 4));
            *(u16x4*)(sl + off) = o4;
        }
    asm volatile("s_waitcnt lgkmcnt(0)" ::: "memory");
    __builtin_amdgcn_sched_barrier(0);

    const int qr = lane >> 1, hf = lane & 1;
    unsigned short* Og = Opart + (size_t)pidx * 128 * 128 +
                         (size_t)(wid * 32 + qr) * 128 + hf * 64;
#pragma unroll
    for (int i = 0; i < 8; ++i) {
        const int off = qr * 256 + ((hf * 128 + i * 16) ^ ((qr & 7) << 4));
        *(u16x8*)(Og + i * 8) = *(const u16x8*)(sl + off);
    }
    if (hi == 0) {
        mpart[(size_t)pidx * 128 + wid * 32 + c5] = m_r;
        lpart[(size_t)pidx * 128 + wid * 32 + c5] = l_r;
    }
#undef GLOAD
#undef SSTORE
}

// ---------------------------------------------------------------------------
// Kernel 2b: combine partials (unchanged).
// ---------------------------------------------------------------------------
__global__ __launch_bounds__(256) void attn_combine(
    const unsigned short* __restrict__ Opart, const float* __restrict__ mpart,
    const float* __restrict__ lpart, float* __restrict__ out)
{
    const int qc = blockIdx.x;
    const int b  = blockIdx.y;
    const int n  = (qc >> 1) + 1;
    const int base = b * 72 + part_offs(qc);
    const int t   = threadIdx.x;
    const int row = t >> 1;
    const int d0  = (t & 1) * 64;

    float M = -INFINITY;
    for (int p = 0; p < n; ++p)
        M = fmaxf(M, mpart[(size_t)(base + p) * 128 + row]);
    float L = 0.f;
    for (int p = 0; p < n; ++p)
        L += __expf(mpart[(size_t)(base + p) * 128 + row] - M) *
             lpart[(size_t)(base + p) * 128 + row];

    float acc[64];
#pragma unroll
    for (int i = 0; i < 64; ++i) acc[i] = 0.f;

    for (int p = 0; p < n; ++p) {
        const float w = __expf(mpart[(size_t)(base + p) * 128 + row] - M);
        const bf16x8* src = (const bf16x8*)(Opart +
            ((size_t)(base + p) * 128 + row) * 128 + d0);
#pragma unroll
        for (int j = 0; j < 8; ++j) {
            bf16x8 v = src[j];
#pragma unroll
            for (int e = 0; e < 8; ++e) {
                union { unsigned u; float f; } x;
                x.u = ((unsigned)(unsigned short)v[e]) << 16;
                acc[j * 8 + e] += w * x.f;
            }
        }
    }

    const float invL = 1.f / L;
    float4* dst = (float4*)(out + ((size_t)(b * TLEN + qc * 128 + row)) * 128 + d0);
#pragma unroll
    for (int i = 0; i < 16; ++i)
        dst[i] = make_float4(acc[4*i] * invL, acc[4*i+1] * invL,
                             acc[4*i+2] * invL, acc[4*i+3] * invL);
}

extern "C" void kernel_launch(void* const* d_in, const int* in_sizes, int n_in,
                              void* d_out, int out_size, void* d_ws, size_t ws_size,
                              hipStream_t stream)
{
    const float* x  = (const float*)d_in[0];
    const float* Wq = (const float*)d_in[1];
    const float* Wk = (const float*)d_in[2];
    const float* Wv = (const float*)d_in[3];
    float* outp = (float*)d_out;

    const size_t per = (size_t)BATCH * TLEN * HDIM;      // 4,194,304
    unsigned short* qb  = (unsigned short*)d_ws;
    unsigned short* kb  = qb + per;
    unsigned short* vtb = kb + per;
    unsigned short* wtb = vtb + per;                     // 384*1024 bf16
    unsigned short* Opart = wtb + 384 * 1024;            // 1152*128*128 bf16
    float* mpart = (float*)(Opart + (size_t)1152 * 128 * 128);
    float* lpart = mpart + (size_t)1152 * 128;

    dim3 gw(512, 3);
    pack_w<<<gw, 256, 0, stream>>>(Wq, Wk, Wv, wtb);

    qkv_fused<<<512, 256, 0, stream>>>(x, wtb, qb, kb, vtb);

    dim3 g2(8, 16, BATCH);
    attn_partial<<<g2, 256, 0, stream>>>((const short*)qb, (const short*)kb,
                                         (const short*)vtb, Opart, mpart, lpart);

    dim3 g3(16, BATCH);
    attn_combine<<<g3, 256, 0, stream>>>(Opart, mpart, lpart, outp);
}

// Round 14
// 139.504 us; speedup vs baseline: 1.4219x; 1.4219x over previous
//
#include <hip/hip_runtime.h>
#include <hip/hip_bf16.h>

#define BATCH 16
#define TLEN 2048
#define CDIM 1024
#define HDIM 128

typedef __attribute__((ext_vector_type(8))) short bf16x8;
typedef __attribute__((ext_vector_type(4))) float f32x4;
typedef __attribute__((ext_vector_type(16))) float f32x16;
typedef __attribute__((ext_vector_type(4))) unsigned short u16x4;
typedef __attribute__((ext_vector_type(8))) unsigned short u16x8;

static __device__ __forceinline__ unsigned short f2bf(float f) {
    __hip_bfloat16 h = __float2bfloat16(f);
    return *(unsigned short*)&h;
}
static __device__ __forceinline__ unsigned pkbf(float a, float b) {
    return (unsigned)f2bf(a) | ((unsigned)f2bf(b) << 16);
}
// partials per (b,qc) prefix:  sum_{j<qc} (j/2 + 1)
static __device__ __forceinline__ int part_offs(int qc) {
    return qc + ((qc * qc - 2 * qc + (qc & 1)) >> 2);
}

typedef const __attribute__((address_space(1))) unsigned int* gas_t;
typedef __attribute__((address_space(3))) unsigned int* las_t;
static __device__ __forceinline__ void gl_lds16(const void* g, void* l) {
    __builtin_amdgcn_global_load_lds((gas_t)g, (las_t)l, 16, 0, 0);
}

// raw barrier pinned against compiler reordering (rule 18 / m201 pattern)
static __device__ __forceinline__ void hard_barrier() {
    __builtin_amdgcn_sched_barrier(0);
    __builtin_amdgcn_s_barrier();
    __builtin_amdgcn_sched_barrier(0);
}

// ---------------------------------------------------------------------------
// Prep: pack Wq|Wk|Wv into transposed bf16  wtb[(which*128+n)*1024 + k].
// ---------------------------------------------------------------------------
__global__ __launch_bounds__(256) void pack_w(
    const float* __restrict__ Wq, const float* __restrict__ Wk,
    const float* __restrict__ Wv, unsigned short* __restrict__ wtb)
{
    const int which = blockIdx.y;
    const float* W = (which == 0) ? Wq : (which == 1) ? Wk : Wv;
    const int n = blockIdx.x >> 2;
    const int k = (blockIdx.x & 3) * 256 + threadIdx.x;
    wtb[((size_t)which * 128 + n) * 1024 + k] = f2bf(W[(size_t)k * 128 + n]);
}

// ---------------------------------------------------------------------------
// Kernel 1: FUSED QKV projection, occupancy-first geometry.
// BM=64, BN=192 (half of q|k|v), BK=32, grid 1024 (512 m-tiles x 2 n-halves),
// 4 waves of 64x48.  LDS 2 x (8KB A-fp32 + 12KB B-bf16) = 40KB -> 4 blocks/CU
// = 16 waves/CU (2x the TLP of all previous variants).  Both operands via
// global_load_lds w16; counted vmcnt(5); raw barriers.  XCD pairing: the two
// n-halves of an m-tile land on the same XCD (x rows shared in L2).
// ---------------------------------------------------------------------------
__global__ __launch_bounds__(256, 4) void qkv_fused(
    const float* __restrict__ x, const unsigned short* __restrict__ wtb,
    unsigned short* __restrict__ qb, unsigned short* __restrict__ kb,
    unsigned short* __restrict__ vtb)
{
    __shared__ __align__(16) float          Axf[2][64 * 32];    // 2 x 8KB  [m][k] f32
    __shared__ __align__(16) unsigned short Bs[2][192 * 32];    // 2 x 12KB [n][k] bf16

    const int xcd = blockIdx.x & 7, s = blockIdx.x >> 3;   // s in 0..127
    const int m0 = (xcd * 64 + (s >> 1)) * 64;             // m-tile, pairs share XCD
    const int nh = s & 1;                                  // 192-col half

    const int tid  = threadIdx.x;
    const int lane = tid & 63, wid = tid >> 6;    // 4 waves = 4 n-slices of 48
    const int c = lane & 15, g = lane >> 4;

    f32x4 acc[4][3];
#pragma unroll
    for (int i = 0; i < 4; ++i)
#pragma unroll
        for (int j = 0; j < 3; ++j) acc[i][j] = (f32x4){0.f, 0.f, 0.f, 0.f};

    // A: 8 segs of 1024B (8 rows x 128B); wave owns segs {2w, 2w+1}.
    //    lane l -> row seg*8 + (l>>3), granule (l&7)^(row&7) (involution).
    // B: 12 segs of 1024B (16 rows x 64B); wave owns segs 3w..3w+2.
    //    lane l -> local row seg*16 + (l>>2), granule (l&3)^((row>>1)&3).
#define STAGE(k0_, bi_)                                                      \
    { _Pragma("unroll")                                                      \
      for (int i_ = 0; i_ < 2; ++i_) {                                       \
          const int seg_ = wid * 2 + i_;                                     \
          const int row_ = seg_ * 8 + (lane >> 3);                           \
          const int col_ = (((lane & 7) ^ (row_ & 7)) << 2);                 \
          gl_lds16(x + (size_t)(m0 + row_) * CDIM + (k0_) + col_,            \
                   (char*)Axf[bi_] + seg_ * 1024);                           \
      }                                                                      \
      _Pragma("unroll")                                                      \
      for (int i_ = 0; i_ < 3; ++i_) {                                       \
          const int seg_ = wid * 3 + i_;                                     \
          const int row_ = seg_ * 16 + (lane >> 2);                          \
          const int col_ = (((lane & 3) ^ ((row_ >> 1) & 3)) << 3);          \
          gl_lds16(wtb + (size_t)(nh * 192 + row_) * 1024 + (k0_) + col_,    \
                   (char*)Bs[bi_] + seg_ * 1024);                            \
      } }

    STAGE(0, 0);    // 5 gl_lds in flight (per wave)

#pragma unroll 1
    for (int kt = 0; kt < 32; ++kt) {
        const int bi = kt & 1;
        if (kt < 31) {
            STAGE((kt + 1) * 32, bi ^ 1);                        // 10 in flight
            asm volatile("s_waitcnt vmcnt(5)" ::: "memory");     // tile kt landed
        } else {
            asm volatile("s_waitcnt vmcnt(0)" ::: "memory");
        }
        hard_barrier();      // all waves' tile-kt loads in LDS

        // ---- fragments from LDS (swizzled reads) ----
        bf16x8 af[4], bf[3];
#pragma unroll
        for (int mf = 0; mf < 4; ++mf) {
            const int rm = mf * 16 + c;
            const char* base = (const char*)Axf[bi] + rm * 128;
            f32x4 lo = *(const f32x4*)(base + ((((2 * g)     ^ (rm & 7)) << 4)));
            f32x4 hi = *(const f32x4*)(base + ((((2 * g + 1) ^ (rm & 7)) << 4)));
            bf16x8 t;
            t[0] = f2bf(lo[0]); t[1] = f2bf(lo[1]); t[2] = f2bf(lo[2]); t[3] = f2bf(lo[3]);
            t[4] = f2bf(hi[0]); t[5] = f2bf(hi[1]); t[6] = f2bf(hi[2]); t[7] = f2bf(hi[3]);
            af[mf] = t;
        }
#pragma unroll
        for (int nf = 0; nf < 3; ++nf) {
            const int rn = wid * 48 + nf * 16 + c;
            bf[nf] = *(const bf16x8*)((const char*)Bs[bi] + rn * 64 +
                                      ((g ^ ((rn >> 1) & 3)) << 4));
        }

        __builtin_amdgcn_s_setprio(1);
#pragma unroll
        for (int mf = 0; mf < 4; ++mf)
#pragma unroll
            for (int nf = 0; nf < 3; ++nf)
                acc[mf][nf] = __builtin_amdgcn_mfma_f32_16x16x32_bf16(
                    af[mf], bf[nf], acc[mf][nf], 0, 0, 0);
        __builtin_amdgcn_s_setprio(0);

        hard_barrier();      // all waves done reading buf bi before restage
    }

    // ---- epilogue: per-fragment route to q (scaled) / k / v^T ----
#pragma unroll
    for (int mf = 0; mf < 4; ++mf) {
#pragma unroll
        for (int nf = 0; nf < 3; ++nf) {
            const int col0 = nh * 192 + wid * 48 + nf * 16;
            const int nt = col0 >> 7;
            const int nc = (col0 & 127) + c;
            const int m = m0 + mf * 16 + g * 4;
            if (nt == 0) {
#pragma unroll
                for (int r = 0; r < 4; ++r)
                    qb[(size_t)(m + r) * HDIM + nc] = f2bf(acc[mf][nf][r] * 0.03125f);
            } else if (nt == 1) {
#pragma unroll
                for (int r = 0; r < 4; ++r)
                    kb[(size_t)(m + r) * HDIM + nc] = f2bf(acc[mf][nf][r]);
            } else {
                const int b = m >> 11, tl = m & (TLEN - 1);
                u16x4 o;
                o[0] = f2bf(acc[mf][nf][0]); o[1] = f2bf(acc[mf][nf][1]);
                o[2] = f2bf(acc[mf][nf][2]); o[3] = f2bf(acc[mf][nf][3]);
                *(u16x4*)(vtb + ((size_t)b * HDIM + nc) * TLEN + tl) = o;
            }
        }
    }
#undef STAGE
}

// ---------------------------------------------------------------------------
// Kernel 2a: flash-attention partials, 32x32 swapped-operand structure
// (unchanged — passed since round 7).
// ---------------------------------------------------------------------------
__global__ __launch_bounds__(256, 2) void attn_partial(
    const short* __restrict__ qb, const short* __restrict__ kb,
    const short* __restrict__ vtb,
    unsigned short* __restrict__ Opart, float* __restrict__ mpart,
    float* __restrict__ lpart)
{
    const int kc = blockIdx.x;
    const int qc = blockIdx.y;
    const int b  = blockIdx.z;
    if (kc > (qc >> 1)) return;
    const int kv_base = kc * 256;
    const int qrel = qc * 128 - kv_base;
    int NT = ((qrel + 127) >> 6) + 1; if (NT > 4) NT = 4;

    __shared__ unsigned short Ks[2][64 * 128];
    __shared__ unsigned short Vs[2][128 * 64];

    const int tid  = threadIdx.x;
    const int wid  = tid >> 6;
    const int lane = tid & 63;
    const int c5 = lane & 31, hi = lane >> 5;
    const int q0w = qc * 128 + wid * 32;
    const int qg  = q0w + c5;
    const int pidx = b * 72 + part_offs(qc) + kc;

    const short* Kb  = kb  + (size_t)b * TLEN * HDIM;
    const short* Vtb = vtb + (size_t)b * HDIM * TLEN;

    bf16x8 qf[8];
#pragma unroll
    for (int ks = 0; ks < 8; ++ks)
        qf[ks] = *(const bf16x8*)(qb + ((size_t)b * TLEN + qg) * HDIM + ks * 16 + hi * 8);

    bf16x8 kst[4], vst[4];

#define GLOAD(kv0_)                                                          \
    {                                                                        \
        _Pragma("unroll")                                                    \
        for (int it = 0; it < 4; ++it) {                                     \
            const int o = tid * 16 + it * 4096;                              \
            const int kr = o >> 8, kcb = o & 0xF0;                           \
            kst[it] = *(const bf16x8*)((const char*)Kb +                     \
                        (size_t)((kv0_) + kr) * 256 + kcb);                  \
            const int vr = o >> 7, vcb = o & 0x70;                           \
            vst[it] = *(const bf16x8*)((const char*)Vtb +                    \
                        (size_t)vr * (TLEN * 2) + (size_t)(kv0_) * 2 + vcb); \
        }                                                                    \
    }
#define SSTORE(bi_)                                                          \
    {                                                                        \
        _Pragma("unroll")                                                    \
        for (int it = 0; it < 4; ++it) {                                     \
            const int o = tid * 16 + it * 4096;                              \
            const int kr = o >> 8, kcb = o & 0xF0;                           \
            *(bf16x8*)((char*)Ks[bi_] + kr * 256 + (kcb ^ ((kr & 7) << 4))) = kst[it]; \
            const int vr = o >> 7, vcb = o & 0x70;                           \
            *(bf16x8*)((char*)Vs[bi_] + vr * 128 + (vcb ^ ((vr & 7) << 4))) = vst[it]; \
        }                                                                    \
    }

    GLOAD(kv_base);
    SSTORE(0);
    __syncthreads();

    f32x16 oacc[4];
#pragma unroll
    for (int i = 0; i < 4; ++i)
#pragma unroll
        for (int r = 0; r < 16; ++r) oacc[i][r] = 0.f;
    float m_r = -1e30f;
    float l_r = 0.f;

#pragma unroll 1
    for (int t = 0; t < NT; ++t) {
        const int bi = t & 1;
        if (t + 1 < NT) GLOAD(kv_base + 64 * (t + 1));

        const int kv0 = kv_base + 64 * t;
        if (kv0 <= q0w + 31) {
            f32x16 s0, s1;
#pragma unroll
            for (int r = 0; r < 16; ++r) { s0[r] = 0.f; s1[r] = 0.f; }
            __builtin_amdgcn_s_setprio(1);
#pragma unroll
            for (int ks = 0; ks < 8; ++ks) {
                const int col = ks * 32 + hi * 16;
                const int off0 = c5 * 256 + (col ^ ((c5 & 7) << 4));
                const int off1 = (32 + c5) * 256 + (col ^ ((c5 & 7) << 4));
                bf16x8 a0 = *(const bf16x8*)((char*)Ks[bi] + off0);
                bf16x8 a1 = *(const bf16x8*)((char*)Ks[bi] + off1);
                s0 = __builtin_amdgcn_mfma_f32_32x32x16_bf16(a0, qf[ks], s0, 0, 0, 0);
                s1 = __builtin_amdgcn_mfma_f32_32x32x16_bf16(a1, qf[ks], s1, 0, 0, 0);
            }
            __builtin_amdgcn_s_setprio(0);

            if (kv0 + 63 > q0w) {
#pragma unroll
                for (int r = 0; r < 16; ++r) {
                    const int key0 = kv0 + (r & 3) + 8 * (r >> 2) + 4 * hi;
                    if (key0 > qg)      s0[r] = -INFINITY;
                    if (key0 + 32 > qg) s1[r] = -INFINITY;
                }
            }

            float t8[8];
#pragma unroll
            for (int i = 0; i < 8; ++i)
                t8[i] = fmaxf(fmaxf(s0[2*i], s0[2*i+1]), fmaxf(s1[2*i], s1[2*i+1]));
            float smax = fmaxf(fmaxf(fmaxf(t8[0], t8[1]), fmaxf(t8[2], t8[3])),
                               fmaxf(fmaxf(t8[4], t8[5]), fmaxf(t8[6], t8[7])));
            smax = fmaxf(smax, __shfl_xor(smax, 32));

            const bool defer = __all(smax - m_r <= 8.0f);   // T13
            const float mnew = defer ? m_r : fmaxf(m_r, smax);
            if (!defer) {
                const float alpha = __expf(m_r - mnew);
                l_r *= alpha;
#pragma unroll
                for (int hb = 0; hb < 4; ++hb) oacc[hb] = oacc[hb] * alpha;
            }
            m_r = mnew;

#pragma unroll
            for (int r = 0; r < 16; ++r) {
                s0[r] = __expf(s0[r] - mnew);
                s1[r] = __expf(s1[r] - mnew);
            }
            float a8[8];
#pragma unroll
            for (int i = 0; i < 8; ++i)
                a8[i] = (s0[2*i] + s0[2*i+1]) + (s1[2*i] + s1[2*i+1]);
            float psum = ((a8[0] + a8[1]) + (a8[2] + a8[3])) +
                         ((a8[4] + a8[5]) + (a8[6] + a8[7]));
            psum += __shfl_xor(psum, 32);
            l_r += psum;

            bf16x8 pa[4];
#pragma unroll
            for (int kb2 = 0; kb2 < 2; ++kb2) {
#pragma unroll
                for (int par = 0; par < 2; ++par) {
                    const int e = par * 8;
                    float v0, v1, v2, v3, v4, v5, v6, v7;
                    if (kb2 == 0) {
                        v0=s0[e+0]; v1=s0[e+1]; v2=s0[e+2]; v3=s0[e+3];
                        v4=s0[e+4]; v5=s0[e+5]; v6=s0[e+6]; v7=s0[e+7];
                    } else {
                        v0=s1[e+0]; v1=s1[e+1]; v2=s1[e+2]; v3=s1[e+3];
                        v4=s1[e+4]; v5=s1[e+5]; v6=s1[e+6]; v7=s1[e+7];
                    }
                    const unsigned w0 = pkbf(v0, v1), w1 = pkbf(v2, v3);
                    const unsigned w2 = pkbf(v4, v5), w3 = pkbf(v6, v7);
                    const unsigned X0 = hi ? w0 : w2;
                    const unsigned X1 = hi ? w1 : w3;
                    const unsigned R0 = (unsigned)__shfl_xor((int)X0, 32);
                    const unsigned R1 = (unsigned)__shfl_xor((int)X1, 32);
                    union { unsigned w[4]; bf16x8 v; } uu;
                    uu.w[0] = hi ? R0 : w0;  uu.w[1] = hi ? R1 : w1;
                    uu.w[2] = hi ? w2 : R0;  uu.w[3] = hi ? w3 : R1;
                    pa[kb2 * 2 + par] = uu.v;
                }
            }

            __builtin_amdgcn_s_setprio(1);
#pragma unroll
            for (int hb = 0; hb < 4; ++hb) {
                const int row = hb * 32 + c5;
#pragma unroll
                for (int ks = 0; ks < 4; ++ks) {
                    const int off = row * 128 + ((ks * 32 + hi * 16) ^ ((row & 7) << 4));
                    bf16x8 va = *(const bf16x8*)((char*)Vs[bi] + off);
                    oacc[hb] = __builtin_amdgcn_mfma_f32_32x32x16_bf16(va, pa[ks], oacc[hb], 0, 0, 0);
                }
            }
            __builtin_amdgcn_s_setprio(0);
        }

        if (t + 1 < NT) {
            SSTORE(bi ^ 1);
            __syncthreads();
        }
    }

    // ---- epilogue: transpose O via LDS, store partials bf16 ----
    __syncthreads();
    char* sl = (char*)Ks + wid * 8192;
#pragma unroll
    for (int hb = 0; hb < 4; ++hb)
#pragma unroll
        for (int rq = 0; rq < 4; ++rq) {
            u16x4 o4;
            o4[0] = f2bf(oacc[hb][rq * 4 + 0]);
            o4[1] = f2bf(oacc[hb][rq * 4 + 1]);
            o4[2] = f2bf(oacc[hb][rq * 4 + 2]);
            o4[3] = f2bf(oacc[hb][rq * 4 + 3]);
            const int off = c5 * 256 + ((hb * 64 + rq * 16 + hi * 8) ^ ((c5 & 7) << 4));
            *(u16x4*)(sl + off) = o4;
        }
    asm volatile("s_waitcnt lgkmcnt(0)" ::: "memory");
    __builtin_amdgcn_sched_barrier(0);

    const int qr = lane >> 1, hf = lane & 1;
    unsigned short* Og = Opart + (size_t)pidx * 128 * 128 +
                         (size_t)(wid * 32 + qr) * 128 + hf * 64;
#pragma unroll
    for (int i = 0; i < 8; ++i) {
        const int off = qr * 256 + ((hf * 128 + i * 16) ^ ((qr & 7) << 4));
        *(u16x8*)(Og + i * 8) = *(const u16x8*)(sl + off);
    }
    if (hi == 0) {
        mpart[(size_t)pidx * 128 + wid * 32 + c5] = m_r;
        lpart[(size_t)pidx * 128 + wid * 32 + c5] = l_r;
    }
#undef GLOAD
#undef SSTORE
}

// ---------------------------------------------------------------------------
// Kernel 2b: combine partials (unchanged).
// ---------------------------------------------------------------------------
__global__ __launch_bounds__(256) void attn_combine(
    const unsigned short* __restrict__ Opart, const float* __restrict__ mpart,
    const float* __restrict__ lpart, float* __restrict__ out)
{
    const int qc = blockIdx.x;
    const int b  = blockIdx.y;
    const int n  = (qc >> 1) + 1;
    const int base = b * 72 + part_offs(qc);
    const int t   = threadIdx.x;
    const int row = t >> 1;
    const int d0  = (t & 1) * 64;

    float M = -INFINITY;
    for (int p = 0; p < n; ++p)
        M = fmaxf(M, mpart[(size_t)(base + p) * 128 + row]);
    float L = 0.f;
    for (int p = 0; p < n; ++p)
        L += __expf(mpart[(size_t)(base + p) * 128 + row] - M) *
             lpart[(size_t)(base + p) * 128 + row];

    float acc[64];
#pragma unroll
    for (int i = 0; i < 64; ++i) acc[i] = 0.f;

    for (int p = 0; p < n; ++p) {
        const float w = __expf(mpart[(size_t)(base + p) * 128 + row] - M);
        const bf16x8* src = (const bf16x8*)(Opart +
            ((size_t)(base + p) * 128 + row) * 128 + d0);
#pragma unroll
        for (int j = 0; j < 8; ++j) {
            bf16x8 v = src[j];
#pragma unroll
            for (int e = 0; e < 8; ++e) {
                union { unsigned u; float f; } x;
                x.u = ((unsigned)(unsigned short)v[e]) << 16;
                acc[j * 8 + e] += w * x.f;
            }
        }
    }

    const float invL = 1.f / L;
    float4* dst = (float4*)(out + ((size_t)(b * TLEN + qc * 128 + row)) * 128 + d0);
#pragma unroll
    for (int i = 0; i < 16; ++i)
        dst[i] = make_float4(acc[4*i] * invL, acc[4*i+1] * invL,
                             acc[4*i+2] * invL, acc[4*i+3] * invL);
}

extern "C" void kernel_launch(void* const* d_in, const int* in_sizes, int n_in,
                              void* d_out, int out_size, void* d_ws, size_t ws_size,
                              hipStream_t stream)
{
    const float* x  = (const float*)d_in[0];
    const float* Wq = (const float*)d_in[1];
    const float* Wk = (const float*)d_in[2];
    const float* Wv = (const float*)d_in[3];
    float* outp = (float*)d_out;

    const size_t per = (size_t)BATCH * TLEN * HDIM;      // 4,194,304
    unsigned short* qb  = (unsigned short*)d_ws;
    unsigned short* kb  = qb + per;
    unsigned short* vtb = kb + per;
    unsigned short* wtb = vtb + per;                     // 384*1024 bf16
    unsigned short* Opart = wtb + 384 * 1024;            // 1152*128*128 bf16
    float* mpart = (float*)(Opart + (size_t)1152 * 128 * 128);
    float* lpart = mpart + (size_t)1152 * 128;

    dim3 gw(512, 3);
    pack_w<<<gw, 256, 0, stream>>>(Wq, Wk, Wv, wtb);

    qkv_fused<<<1024, 256, 0, stream>>>(x, wtb, qb, kb, vtb);

    dim3 g2(8, 16, BATCH);
    attn_partial<<<g2, 256, 0, stream>>>((const short*)qb, (const short*)kb,
                                         (const short*)vtb, Opart, mpart, lpart);

    dim3 g3(16, BATCH);
    attn_combine<<<g3, 256, 0, stream>>>(Opart, mpart, lpart, outp);
}

// Round 15
// 136.726 us; speedup vs baseline: 1.4508x; 1.0203x over previous
//
#include <hip/hip_runtime.h>
#include <hip/hip_bf16.h>

#define BATCH 16
#define TLEN 2048
#define CDIM 1024
#define HDIM 128

typedef __attribute__((ext_vector_type(8))) short bf16x8;
typedef __attribute__((ext_vector_type(4))) float f32x4;
typedef __attribute__((ext_vector_type(16))) float f32x16;
typedef __attribute__((ext_vector_type(4))) unsigned short u16x4;
typedef __attribute__((ext_vector_type(8))) unsigned short u16x8;

static __device__ __forceinline__ unsigned short f2bf(float f) {
    __hip_bfloat16 h = __float2bfloat16(f);
    return *(unsigned short*)&h;
}
static __device__ __forceinline__ unsigned pkbf(float a, float b) {
    return (unsigned)f2bf(a) | ((unsigned)f2bf(b) << 16);
}
// partials per (b,qc) prefix:  sum_{j<qc} (j/2 + 1)
static __device__ __forceinline__ int part_offs(int qc) {
    return qc + ((qc * qc - 2 * qc + (qc & 1)) >> 2);
}

typedef const __attribute__((address_space(1))) unsigned int* gas_t;
typedef __attribute__((address_space(3))) unsigned int* las_t;
static __device__ __forceinline__ void gl_lds16(const void* g, void* l) {
    __builtin_amdgcn_global_load_lds((gas_t)g, (las_t)l, 16, 0, 0);
}

// raw barrier pinned against compiler reordering (rule 18 / m201 pattern)
static __device__ __forceinline__ void hard_barrier() {
    __builtin_amdgcn_sched_barrier(0);
    __builtin_amdgcn_s_barrier();
    __builtin_amdgcn_sched_barrier(0);
}

// ---------------------------------------------------------------------------
// Prep: pack Wq|Wk|Wv into transposed bf16  wtb[(which*128+n)*1024 + k].
// ---------------------------------------------------------------------------
__global__ __launch_bounds__(256) void pack_w(
    const float* __restrict__ Wq, const float* __restrict__ Wk,
    const float* __restrict__ Wv, unsigned short* __restrict__ wtb)
{
    const int which = blockIdx.y;
    const float* W = (which == 0) ? Wq : (which == 1) ? Wk : Wv;
    const int n = blockIdx.x >> 2;
    const int k = (blockIdx.x & 3) * 256 + threadIdx.x;
    wtb[((size_t)which * 128 + n) * 1024 + k] = f2bf(W[(size_t)k * 128 + n]);
}

// ---------------------------------------------------------------------------
// Kernel 1: FUSED QKV projection — BK=64 (16 K-steps, discriminating test
// of fixed-per-step overhead vs byte-throughput).
// BM=64, BN=192, BK=64, grid 1024 (512 m-tiles x 2 n-halves), 4 waves of
// 64x48, 24 MFMA/wave/step.  LDS 2 x (16KB A-fp32 + 24KB B-bf16) = 80KB ->
// 2 blocks/CU.  gl_lds w16 both operands; counted vmcnt(10); raw barriers.
// Swizzles are true involutions for this geometry:
//   A (256B rows, 16 granules): gran ^= rm & 15
//   B (128B rows,  8 granules): gran ^= rn & 7
// applied on the pre-swizzled global SOURCE and the LDS READ (rule 21).
// ---------------------------------------------------------------------------
__global__ __launch_bounds__(256, 2) void qkv_fused(
    const float* __restrict__ x, const unsigned short* __restrict__ wtb,
    unsigned short* __restrict__ qb, unsigned short* __restrict__ kb,
    unsigned short* __restrict__ vtb)
{
    __shared__ __align__(16) float          Axf[2][64 * 64];    // 2 x 16KB [m][k] f32
    __shared__ __align__(16) unsigned short Bs[2][192 * 64];    // 2 x 24KB [n][k] bf16

    const int xcd = blockIdx.x & 7, s = blockIdx.x >> 3;   // s in 0..127
    const int m0 = (xcd * 64 + (s >> 1)) * 64;             // m-tile; pairs share XCD
    const int nh = s & 1;                                  // 192-col half

    const int tid  = threadIdx.x;
    const int lane = tid & 63, wid = tid >> 6;    // 4 waves = 4 n-slices of 48
    const int c = lane & 15, g = lane >> 4;

    f32x4 acc[4][3];
#pragma unroll
    for (int i = 0; i < 4; ++i)
#pragma unroll
        for (int j = 0; j < 3; ++j) acc[i][j] = (f32x4){0.f, 0.f, 0.f, 0.f};

    // A: 16 segs of 1024B (4 rows x 256B); wave owns segs 4w..4w+3.
    //    lane l -> row seg*4 + (l>>4), src granule (l&15)^(row&15).
    // B: 24 segs of 1024B (8 rows x 128B); wave owns segs 6w..6w+5.
    //    lane l -> row seg*8 + (l>>3), src granule (l&7)^(row&7).
#define STAGE(k0_, bi_)                                                      \
    { _Pragma("unroll")                                                      \
      for (int i_ = 0; i_ < 4; ++i_) {                                       \
          const int seg_ = wid * 4 + i_;                                     \
          const int row_ = seg_ * 4 + (lane >> 4);                           \
          const int sg_  = (lane & 15) ^ (row_ & 15);                        \
          gl_lds16(x + (size_t)(m0 + row_) * CDIM + (k0_) + sg_ * 4,         \
                   (char*)Axf[bi_] + seg_ * 1024);                           \
      }                                                                      \
      _Pragma("unroll")                                                      \
      for (int i_ = 0; i_ < 6; ++i_) {                                       \
          const int seg_ = wid * 6 + i_;                                     \
          const int row_ = seg_ * 8 + (lane >> 3);                           \
          const int sg_  = (lane & 7) ^ (row_ & 7);                          \
          gl_lds16(wtb + (size_t)(nh * 192 + row_) * 1024 + (k0_) + sg_ * 8, \
                   (char*)Bs[bi_] + seg_ * 1024);                            \
      } }

    STAGE(0, 0);    // 10 gl_lds in flight (per wave)

#pragma unroll 1
    for (int kt = 0; kt < 16; ++kt) {
        const int bi = kt & 1;
        if (kt < 15) {
            STAGE((kt + 1) * 64, bi ^ 1);                        // 20 in flight
            asm volatile("s_waitcnt vmcnt(10)" ::: "memory");    // tile kt landed
        } else {
            asm volatile("s_waitcnt vmcnt(0)" ::: "memory");
        }
        hard_barrier();      // all waves' tile-kt loads in LDS

#pragma unroll
        for (int ks = 0; ks < 2; ++ks) {
            // ---- fragments from LDS (involution-swizzled reads) ----
            bf16x8 af[4], bf[3];
#pragma unroll
            for (int mf = 0; mf < 4; ++mf) {
                const int rm = mf * 16 + c;
                const float* base = Axf[bi] + rm * 64;
                const int g0 = (ks * 8 + 2 * g)     ^ (rm & 15);
                const int g1 = (ks * 8 + 2 * g + 1) ^ (rm & 15);
                f32x4 lo = *(const f32x4*)(base + g0 * 4);
                f32x4 hi = *(const f32x4*)(base + g1 * 4);
                bf16x8 t;
                t[0] = f2bf(lo[0]); t[1] = f2bf(lo[1]); t[2] = f2bf(lo[2]); t[3] = f2bf(lo[3]);
                t[4] = f2bf(hi[0]); t[5] = f2bf(hi[1]); t[6] = f2bf(hi[2]); t[7] = f2bf(hi[3]);
                af[mf] = t;
            }
#pragma unroll
            for (int nf = 0; nf < 3; ++nf) {
                const int rn = wid * 48 + nf * 16 + c;
                const int gb = (ks * 4 + g) ^ (rn & 7);
                bf[nf] = *(const bf16x8*)((char*)Bs[bi] + rn * 128 + gb * 16);
            }

            __builtin_amdgcn_s_setprio(1);
#pragma unroll
            for (int mf = 0; mf < 4; ++mf)
#pragma unroll
                for (int nf = 0; nf < 3; ++nf)
                    acc[mf][nf] = __builtin_amdgcn_mfma_f32_16x16x32_bf16(
                        af[mf], bf[nf], acc[mf][nf], 0, 0, 0);
            __builtin_amdgcn_s_setprio(0);
        }

        hard_barrier();      // all waves done reading buf bi before restage
    }

    // ---- epilogue: per-fragment route to q (scaled) / k / v^T ----
#pragma unroll
    for (int mf = 0; mf < 4; ++mf) {
#pragma unroll
        for (int nf = 0; nf < 3; ++nf) {
            const int col0 = nh * 192 + wid * 48 + nf * 16;
            const int nt = col0 >> 7;
            const int nc = (col0 & 127) + c;
            const int m = m0 + mf * 16 + g * 4;
            if (nt == 0) {
#pragma unroll
                for (int r = 0; r < 4; ++r)
                    qb[(size_t)(m + r) * HDIM + nc] = f2bf(acc[mf][nf][r] * 0.03125f);
            } else if (nt == 1) {
#pragma unroll
                for (int r = 0; r < 4; ++r)
                    kb[(size_t)(m + r) * HDIM + nc] = f2bf(acc[mf][nf][r]);
            } else {
                const int b = m >> 11, tl = m & (TLEN - 1);
                u16x4 o;
                o[0] = f2bf(acc[mf][nf][0]); o[1] = f2bf(acc[mf][nf][1]);
                o[2] = f2bf(acc[mf][nf][2]); o[3] = f2bf(acc[mf][nf][3]);
                *(u16x4*)(vtb + ((size_t)b * HDIM + nc) * TLEN + tl) = o;
            }
        }
    }
#undef STAGE
}

// ---------------------------------------------------------------------------
// Kernel 2a: flash-attention partials, 32x32 swapped-operand structure
// (unchanged — passed since round 7).
// ---------------------------------------------------------------------------
__global__ __launch_bounds__(256, 2) void attn_partial(
    const short* __restrict__ qb, const short* __restrict__ kb,
    const short* __restrict__ vtb,
    unsigned short* __restrict__ Opart, float* __restrict__ mpart,
    float* __restrict__ lpart)
{
    const int kc = blockIdx.x;
    const int qc = blockIdx.y;
    const int b  = blockIdx.z;
    if (kc > (qc >> 1)) return;
    const int kv_base = kc * 256;
    const int qrel = qc * 128 - kv_base;
    int NT = ((qrel + 127) >> 6) + 1; if (NT > 4) NT = 4;

    __shared__ unsigned short Ks[2][64 * 128];
    __shared__ unsigned short Vs[2][128 * 64];

    const int tid  = threadIdx.x;
    const int wid  = tid >> 6;
    const int lane = tid & 63;
    const int c5 = lane & 31, hi = lane >> 5;
    const int q0w = qc * 128 + wid * 32;
    const int qg  = q0w + c5;
    const int pidx = b * 72 + part_offs(qc) + kc;

    const short* Kb  = kb  + (size_t)b * TLEN * HDIM;
    const short* Vtb = vtb + (size_t)b * HDIM * TLEN;

    bf16x8 qf[8];
#pragma unroll
    for (int ks = 0; ks < 8; ++ks)
        qf[ks] = *(const bf16x8*)(qb + ((size_t)b * TLEN + qg) * HDIM + ks * 16 + hi * 8);

    bf16x8 kst[4], vst[4];

#define GLOAD(kv0_)                                                          \
    {                                                                        \
        _Pragma("unroll")                                                    \
        for (int it = 0; it < 4; ++it) {                                     \
            const int o = tid * 16 + it * 4096;                              \
            const int kr = o >> 8, kcb = o & 0xF0;                           \
            kst[it] = *(const bf16x8*)((const char*)Kb +                     \
                        (size_t)((kv0_) + kr) * 256 + kcb);                  \
            const int vr = o >> 7, vcb = o & 0x70;                           \
            vst[it] = *(const bf16x8*)((const char*)Vtb +                    \
                        (size_t)vr * (TLEN * 2) + (size_t)(kv0_) * 2 + vcb); \
        }                                                                    \
    }
#define SSTORE(bi_)                                                          \
    {                                                                        \
        _Pragma("unroll")                                                    \
        for (int it = 0; it < 4; ++it) {                                     \
            const int o = tid * 16 + it * 4096;                              \
            const int kr = o >> 8, kcb = o & 0xF0;                           \
            *(bf16x8*)((char*)Ks[bi_] + kr * 256 + (kcb ^ ((kr & 7) << 4))) = kst[it]; \
            const int vr = o >> 7, vcb = o & 0x70;                           \
            *(bf16x8*)((char*)Vs[bi_] + vr * 128 + (vcb ^ ((vr & 7) << 4))) = vst[it]; \
        }                                                                    \
    }

    GLOAD(kv_base);
    SSTORE(0);
    __syncthreads();

    f32x16 oacc[4];
#pragma unroll
    for (int i = 0; i < 4; ++i)
#pragma unroll
        for (int r = 0; r < 16; ++r) oacc[i][r] = 0.f;
    float m_r = -1e30f;
    float l_r = 0.f;

#pragma unroll 1
    for (int t = 0; t < NT; ++t) {
        const int bi = t & 1;
        if (t + 1 < NT) GLOAD(kv_base + 64 * (t + 1));

        const int kv0 = kv_base + 64 * t;
        if (kv0 <= q0w + 31) {
            f32x16 s0, s1;
#pragma unroll
            for (int r = 0; r < 16; ++r) { s0[r] = 0.f; s1[r] = 0.f; }
            __builtin_amdgcn_s_setprio(1);
#pragma unroll
            for (int ks = 0; ks < 8; ++ks) {
                const int col = ks * 32 + hi * 16;
                const int off0 = c5 * 256 + (col ^ ((c5 & 7) << 4));
                const int off1 = (32 + c5) * 256 + (col ^ ((c5 & 7) << 4));
                bf16x8 a0 = *(const bf16x8*)((char*)Ks[bi] + off0);
                bf16x8 a1 = *(const bf16x8*)((char*)Ks[bi] + off1);
                s0 = __builtin_amdgcn_mfma_f32_32x32x16_bf16(a0, qf[ks], s0, 0, 0, 0);
                s1 = __builtin_amdgcn_mfma_f32_32x32x16_bf16(a1, qf[ks], s1, 0, 0, 0);
            }
            __builtin_amdgcn_s_setprio(0);

            if (kv0 + 63 > q0w) {
#pragma unroll
                for (int r = 0; r < 16; ++r) {
                    const int key0 = kv0 + (r & 3) + 8 * (r >> 2) + 4 * hi;
                    if (key0 > qg)      s0[r] = -INFINITY;
                    if (key0 + 32 > qg) s1[r] = -INFINITY;
                }
            }

            float t8[8];
#pragma unroll
            for (int i = 0; i < 8; ++i)
                t8[i] = fmaxf(fmaxf(s0[2*i], s0[2*i+1]), fmaxf(s1[2*i], s1[2*i+1]));
            float smax = fmaxf(fmaxf(fmaxf(t8[0], t8[1]), fmaxf(t8[2], t8[3])),
                               fmaxf(fmaxf(t8[4], t8[5]), fmaxf(t8[6], t8[7])));
            smax = fmaxf(smax, __shfl_xor(smax, 32));

            const bool defer = __all(smax - m_r <= 8.0f);   // T13
            const float mnew = defer ? m_r : fmaxf(m_r, smax);
            if (!defer) {
                const float alpha = __expf(m_r - mnew);
                l_r *= alpha;
#pragma unroll
                for (int hb = 0; hb < 4; ++hb) oacc[hb] = oacc[hb] * alpha;
            }
            m_r = mnew;

#pragma unroll
            for (int r = 0; r < 16; ++r) {
                s0[r] = __expf(s0[r] - mnew);
                s1[r] = __expf(s1[r] - mnew);
            }
            float a8[8];
#pragma unroll
            for (int i = 0; i < 8; ++i)
                a8[i] = (s0[2*i] + s0[2*i+1]) + (s1[2*i] + s1[2*i+1]);
            float psum = ((a8[0] + a8[1]) + (a8[2] + a8[3])) +
                         ((a8[4] + a8[5]) + (a8[6] + a8[7]));
            psum += __shfl_xor(psum, 32);
            l_r += psum;

            bf16x8 pa[4];
#pragma unroll
            for (int kb2 = 0; kb2 < 2; ++kb2) {
#pragma unroll
                for (int par = 0; par < 2; ++par) {
                    const int e = par * 8;
                    float v0, v1, v2, v3, v4, v5, v6, v7;
                    if (kb2 == 0) {
                        v0=s0[e+0]; v1=s0[e+1]; v2=s0[e+2]; v3=s0[e+3];
                        v4=s0[e+4]; v5=s0[e+5]; v6=s0[e+6]; v7=s0[e+7];
                    } else {
                        v0=s1[e+0]; v1=s1[e+1]; v2=s1[e+2]; v3=s1[e+3];
                        v4=s1[e+4]; v5=s1[e+5]; v6=s1[e+6]; v7=s1[e+7];
                    }
                    const unsigned w0 = pkbf(v0, v1), w1 = pkbf(v2, v3);
                    const unsigned w2 = pkbf(v4, v5), w3 = pkbf(v6, v7);
                    const unsigned X0 = hi ? w0 : w2;
                    const unsigned X1 = hi ? w1 : w3;
                    const unsigned R0 = (unsigned)__shfl_xor((int)X0, 32);
                    const unsigned R1 = (unsigned)__shfl_xor((int)X1, 32);
                    union { unsigned w[4]; bf16x8 v; } uu;
                    uu.w[0] = hi ? R0 : w0;  uu.w[1] = hi ? R1 : w1;
                    uu.w[2] = hi ? w2 : R0;  uu.w[3] = hi ? w3 : R1;
                    pa[kb2 * 2 + par] = uu.v;
                }
            }

            __builtin_amdgcn_s_setprio(1);
#pragma unroll
            for (int hb = 0; hb < 4; ++hb) {
                const int row = hb * 32 + c5;
#pragma unroll
                for (int ks = 0; ks < 4; ++ks) {
                    const int off = row * 128 + ((ks * 32 + hi * 16) ^ ((row & 7) << 4));
                    bf16x8 va = *(const bf16x8*)((char*)Vs[bi] + off);
                    oacc[hb] = __builtin_amdgcn_mfma_f32_32x32x16_bf16(va, pa[ks], oacc[hb], 0, 0, 0);
                }
            }
            __builtin_amdgcn_s_setprio(0);
        }

        if (t + 1 < NT) {
            SSTORE(bi ^ 1);
            __syncthreads();
        }
    }

    // ---- epilogue: transpose O via LDS, store partials bf16 ----
    __syncthreads();
    char* sl = (char*)Ks + wid * 8192;
#pragma unroll
    for (int hb = 0; hb < 4; ++hb)
#pragma unroll
        for (int rq = 0; rq < 4; ++rq) {
            u16x4 o4;
            o4[0] = f2bf(oacc[hb][rq * 4 + 0]);
            o4[1] = f2bf(oacc[hb][rq * 4 + 1]);
            o4[2] = f2bf(oacc[hb][rq * 4 + 2]);
            o4[3] = f2bf(oacc[hb][rq * 4 + 3]);
            const int off = c5 * 256 + ((hb * 64 + rq * 16 + hi * 8) ^ ((c5 & 7) << 4));
            *(u16x4*)(sl + off) = o4;
        }
    asm volatile("s_waitcnt lgkmcnt(0)" ::: "memory");
    __builtin_amdgcn_sched_barrier(0);

    const int qr = lane >> 1, hf = lane & 1;
    unsigned short* Og = Opart + (size_t)pidx * 128 * 128 +
                         (size_t)(wid * 32 + qr) * 128 + hf * 64;
#pragma unroll
    for (int i = 0; i < 8; ++i) {
        const int off = qr * 256 + ((hf * 128 + i * 16) ^ ((qr & 7) << 4));
        *(u16x8*)(Og + i * 8) = *(const u16x8*)(sl + off);
    }
    if (hi == 0) {
        mpart[(size_t)pidx * 128 + wid * 32 + c5] = m_r;
        lpart[(size_t)pidx * 128 + wid * 32 + c5] = l_r;
    }
#undef GLOAD
#undef SSTORE
}

// ---------------------------------------------------------------------------
// Kernel 2b: combine partials (unchanged).
// ---------------------------------------------------------------------------
__global__ __launch_bounds__(256) void attn_combine(
    const unsigned short* __restrict__ Opart, const float* __restrict__ mpart,
    const float* __restrict__ lpart, float* __restrict__ out)
{
    const int qc = blockIdx.x;
    const int b  = blockIdx.y;
    const int n  = (qc >> 1) + 1;
    const int base = b * 72 + part_offs(qc);
    const int t   = threadIdx.x;
    const int row = t >> 1;
    const int d0  = (t & 1) * 64;

    float M = -INFINITY;
    for (int p = 0; p < n; ++p)
        M = fmaxf(M, mpart[(size_t)(base + p) * 128 + row]);
    float L = 0.f;
    for (int p = 0; p < n; ++p)
        L += __expf(mpart[(size_t)(base + p) * 128 + row] - M) *
             lpart[(size_t)(base + p) * 128 + row];

    float acc[64];
#pragma unroll
    for (int i = 0; i < 64; ++i) acc[i] = 0.f;

    for (int p = 0; p < n; ++p) {
        const float w = __expf(mpart[(size_t)(base + p) * 128 + row] - M);
        const bf16x8* src = (const bf16x8*)(Opart +
            ((size_t)(base + p) * 128 + row) * 128 + d0);
#pragma unroll
        for (int j = 0; j < 8; ++j) {
            bf16x8 v = src[j];
#pragma unroll
            for (int e = 0; e < 8; ++e) {
                union { unsigned u; float f; } x;
                x.u = ((unsigned)(unsigned short)v[e]) << 16;
                acc[j * 8 + e] += w * x.f;
            }
        }
    }

    const float invL = 1.f / L;
    float4* dst = (float4*)(out + ((size_t)(b * TLEN + qc * 128 + row)) * 128 + d0);
#pragma unroll
    for (int i = 0; i < 16; ++i)
        dst[i] = make_float4(acc[4*i] * invL, acc[4*i+1] * invL,
                             acc[4*i+2] * invL, acc[4*i+3] * invL);
}

extern "C" void kernel_launch(void* const* d_in, const int* in_sizes, int n_in,
                              void* d_out, int out_size, void* d_ws, size_t ws_size,
                              hipStream_t stream)
{
    const float* x  = (const float*)d_in[0];
    const float* Wq = (const float*)d_in[1];
    const float* Wk = (const float*)d_in[2];
    const float* Wv = (const float*)d_in[3];
    float* outp = (float*)d_out;

    const size_t per = (size_t)BATCH * TLEN * HDIM;      // 4,194,304
    unsigned short* qb  = (unsigned short*)d_ws;
    unsigned short* kb  = qb + per;
    unsigned short* vtb = kb + per;
    unsigned short* wtb = vtb + per;                     // 384*1024 bf16
    unsigned short* Opart = wtb + 384 * 1024;            // 1152*128*128 bf16
    float* mpart = (float*)(Opart + (size_t)1152 * 128 * 128);
    float* lpart = mpart + (size_t)1152 * 128;

    dim3 gw(512, 3);
    pack_w<<<gw, 256, 0, stream>>>(Wq, Wk, Wv, wtb);

    qkv_fused<<<1024, 256, 0, stream>>>(x, wtb, qb, kb, vtb);

    dim3 g2(8, 16, BATCH);
    attn_partial<<<g2, 256, 0, stream>>>((const short*)qb, (const short*)kb,
                                         (const short*)vtb, Opart, mpart, lpart);

    dim3 g3(16, BATCH);
    attn_combine<<<g3, 256, 0, stream>>>(Opart, mpart, lpart, outp);
}

// Round 16
// 130.004 us; speedup vs baseline: 1.5258x; 1.0517x over previous
//
#include <hip/hip_runtime.h>
#include <hip/hip_bf16.h>

#define BATCH 16
#define TLEN 2048
#define CDIM 1024
#define HDIM 128

typedef __attribute__((ext_vector_type(8))) short bf16x8;
typedef __attribute__((ext_vector_type(4))) float f32x4;
typedef __attribute__((ext_vector_type(16))) float f32x16;
typedef __attribute__((ext_vector_type(4))) unsigned short u16x4;
typedef __attribute__((ext_vector_type(8))) unsigned short u16x8;

static __device__ __forceinline__ unsigned short f2bf(float f) {
    __hip_bfloat16 h = __float2bfloat16(f);
    return *(unsigned short*)&h;
}
static __device__ __forceinline__ unsigned pkbf(float a, float b) {
    return (unsigned)f2bf(a) | ((unsigned)f2bf(b) << 16);
}
// partials per (b,qc) prefix:  sum_{j<qc} (j/2 + 1)
static __device__ __forceinline__ int part_offs(int qc) {
    return qc + ((qc * qc - 2 * qc + (qc & 1)) >> 2);
}

typedef const __attribute__((address_space(1))) unsigned int* gas_t;
typedef __attribute__((address_space(3))) unsigned int* las_t;
static __device__ __forceinline__ void gl_lds16(const void* g, void* l) {
    __builtin_amdgcn_global_load_lds((gas_t)g, (las_t)l, 16, 0, 0);
}

// raw barrier pinned against compiler reordering (rule 18 / m201 pattern)
static __device__ __forceinline__ void hard_barrier() {
    __builtin_amdgcn_sched_barrier(0);
    __builtin_amdgcn_s_barrier();
    __builtin_amdgcn_sched_barrier(0);
}

// ---------------------------------------------------------------------------
// Prep: pack Wq|Wk|Wv into transposed bf16  wtb[(which*128+n)*1024 + k].
// ---------------------------------------------------------------------------
__global__ __launch_bounds__(256) void pack_w(
    const float* __restrict__ Wq, const float* __restrict__ Wk,
    const float* __restrict__ Wv, unsigned short* __restrict__ wtb)
{
    const int which = blockIdx.y;
    const float* W = (which == 0) ? Wq : (which == 1) ? Wk : Wv;
    const int n = blockIdx.x >> 2;
    const int k = (blockIdx.x & 3) * 256 + threadIdx.x;
    wtb[((size_t)which * 128 + n) * 1024 + k] = f2bf(W[(size_t)k * 128 + n]);
}

// ---------------------------------------------------------------------------
// Kernel 1: FUSED QKV projection — m248-shaped 2-phase.
// BM=128, BN=192, BK=64, 512 thr / 8 waves (2m x 4n, wave-tile 64x48),
// grid 512 (256 m-tiles x 2 n-halves, XCD-paired).  LDS 80KB -> 2 blocks/CU
// = 4 waves/SIMD.  A: fp32 x reg-staged -> bf16 LDS via T14 split (loads
// issued BEFORE compute, cvt+ds_write AFTER, off the ds_read->MFMA path).
// B: gl_lds w16 pre-swizzled.  Involution swizzle both sides; counted
// vmcnt(3); one barrier per K-step; setprio around MFMA.
// ---------------------------------------------------------------------------
__global__ __launch_bounds__(512, 4) void qkv_fused(
    const float* __restrict__ x, const unsigned short* __restrict__ wtb,
    unsigned short* __restrict__ qb, unsigned short* __restrict__ kb,
    unsigned short* __restrict__ vtb)
{
    __shared__ __align__(16) unsigned short Ab[2][128 * 64];   // 2 x 16KB [m][k] bf16
    __shared__ __align__(16) unsigned short Bb[2][192 * 64];   // 2 x 24KB [n][k] bf16

    const int xcd = blockIdx.x & 7, s = blockIdx.x >> 3;   // s in 0..63
    const int m0 = (xcd * 32 + (s >> 1)) * 128;            // 256 m-tiles, pairs share XCD
    const int nh = s & 1;                                  // 192-col half

    const int tid  = threadIdx.x;
    const int lane = tid & 63, wid = tid >> 6;    // 8 waves: 2m x 4n
    const int wm = wid >> 2, wn = wid & 3;
    const int c = lane & 15, g = lane >> 4;

    // A staging: thread -> row tid>>2 (0..127), k-quarter tid&3 (16 elems)
    const int arow = tid >> 2, aq = tid & 3;
    const float* xsrc = x + (size_t)(m0 + arow) * CDIM + aq * 16;

    f32x4 acc[4][3];
#pragma unroll
    for (int i = 0; i < 4; ++i)
#pragma unroll
        for (int j = 0; j < 3; ++j) acc[i][j] = (f32x4){0.f, 0.f, 0.f, 0.f};

    float4 As0, As1, As2, As3;     // A stage registers (16 fp32)

#define AISSUE(k0_)                                                          \
    { const float* s_ = xsrc + (k0_);                                        \
      As0 = *(const float4*)(s_);      As1 = *(const float4*)(s_ + 4);       \
      As2 = *(const float4*)(s_ + 8);  As3 = *(const float4*)(s_ + 12); }

#define AWRITE(bi_)                                                          \
    { u16x8 t0_, t1_;                                                        \
      t0_[0]=f2bf(As0.x); t0_[1]=f2bf(As0.y); t0_[2]=f2bf(As0.z); t0_[3]=f2bf(As0.w); \
      t0_[4]=f2bf(As1.x); t0_[5]=f2bf(As1.y); t0_[6]=f2bf(As1.z); t0_[7]=f2bf(As1.w); \
      t1_[0]=f2bf(As2.x); t1_[1]=f2bf(As2.y); t1_[2]=f2bf(As2.z); t1_[3]=f2bf(As2.w); \
      t1_[4]=f2bf(As3.x); t1_[5]=f2bf(As3.y); t1_[6]=f2bf(As3.z); t1_[7]=f2bf(As3.w); \
      char* ba_ = (char*)Ab[bi_] + arow * 128;                               \
      *(u16x8*)(ba_ + ((aq * 32 +  0) ^ ((arow & 7) << 4))) = t0_;           \
      *(u16x8*)(ba_ + ((aq * 32 + 16) ^ ((arow & 7) << 4))) = t1_; }

    // B: 24 segs of 1024B (8 rows x 128B); wave owns segs 3w..3w+2.
    //    lane l -> row seg*8 + (l>>3); source granule (l&7)^(row&7).
#define BISSUE(k0_, bi_)                                                     \
    { _Pragma("unroll")                                                      \
      for (int i_ = 0; i_ < 3; ++i_) {                                       \
          const int seg_ = wid * 3 + i_;                                     \
          const int row_ = seg_ * 8 + (lane >> 3);                           \
          const int gr_  = (lane & 7) ^ (row_ & 7);                          \
          gl_lds16(wtb + (size_t)(nh * 192 + row_) * 1024 + (k0_) + gr_ * 8, \
                   (char*)Bb[bi_] + seg_ * 1024);                            \
      } }

    // prologue: fill buffer 0
    AISSUE(0);
    BISSUE(0, 0);
    asm volatile("s_waitcnt vmcnt(3)" ::: "memory");   // A(0) landed
    AWRITE(0);
    asm volatile("s_waitcnt vmcnt(0) lgkmcnt(0)" ::: "memory");
    hard_barrier();

#pragma unroll 1
    for (int kt = 0; kt < 16; ++kt) {
        const int cur = kt & 1;
        if (kt < 15) {                       // issue next tile BEFORE compute
            AISSUE((kt + 1) * 64);
            BISSUE((kt + 1) * 64, cur ^ 1);
        }

        // ---- compute tile kt from LDS (bf16, swizzled reads) ----
#pragma unroll
        for (int ks = 0; ks < 2; ++ks) {
            bf16x8 af[4], bf[3];
#pragma unroll
            for (int mf = 0; mf < 4; ++mf) {
                const int rm = wm * 64 + mf * 16 + c;
                af[mf] = *(const bf16x8*)((char*)Ab[cur] + rm * 128 +
                                          ((ks * 64 + g * 16) ^ ((rm & 7) << 4)));
            }
#pragma unroll
            for (int nf = 0; nf < 3; ++nf) {
                const int rn = wn * 48 + nf * 16 + c;
                bf[nf] = *(const bf16x8*)((char*)Bb[cur] + rn * 128 +
                                          ((ks * 64 + g * 16) ^ ((rn & 7) << 4)));
            }
            __builtin_amdgcn_s_setprio(1);
#pragma unroll
            for (int mf = 0; mf < 4; ++mf)
#pragma unroll
                for (int nf = 0; nf < 3; ++nf)
                    acc[mf][nf] = __builtin_amdgcn_mfma_f32_16x16x32_bf16(
                        af[mf], bf[nf], acc[mf][nf], 0, 0, 0);
            __builtin_amdgcn_s_setprio(0);
        }

        if (kt < 15) {
            asm volatile("s_waitcnt vmcnt(3)" ::: "memory");   // A(kt+1) in regs
            AWRITE(cur ^ 1);                                   // cvt + swizzled write
            asm volatile("s_waitcnt vmcnt(0) lgkmcnt(0)" ::: "memory");
            hard_barrier();
        }
    }

    // ---- epilogue: per-fragment route to q (scaled) / k / v^T ----
#pragma unroll
    for (int mf = 0; mf < 4; ++mf) {
#pragma unroll
        for (int nf = 0; nf < 3; ++nf) {
            const int col0 = nh * 192 + wn * 48 + nf * 16;
            const int nt = col0 >> 7;
            const int nc = (col0 & 127) + c;
            const int m = m0 + wm * 64 + mf * 16 + g * 4;
            if (nt == 0) {
#pragma unroll
                for (int r = 0; r < 4; ++r)
                    qb[(size_t)(m + r) * HDIM + nc] = f2bf(acc[mf][nf][r] * 0.03125f);
            } else if (nt == 1) {
#pragma unroll
                for (int r = 0; r < 4; ++r)
                    kb[(size_t)(m + r) * HDIM + nc] = f2bf(acc[mf][nf][r]);
            } else {
                const int b = m >> 11, tl = m & (TLEN - 1);
                u16x4 o;
                o[0] = f2bf(acc[mf][nf][0]); o[1] = f2bf(acc[mf][nf][1]);
                o[2] = f2bf(acc[mf][nf][2]); o[3] = f2bf(acc[mf][nf][3]);
                *(u16x4*)(vtb + ((size_t)b * HDIM + nc) * TLEN + tl) = o;
            }
        }
    }
#undef AISSUE
#undef AWRITE
#undef BISSUE
}

// ---------------------------------------------------------------------------
// Kernel 2a: flash-attention partials, 32x32 swapped-operand structure
// (unchanged — passed since round 7).
// ---------------------------------------------------------------------------
__global__ __launch_bounds__(256, 2) void attn_partial(
    const short* __restrict__ qb, const short* __restrict__ kb,
    const short* __restrict__ vtb,
    unsigned short* __restrict__ Opart, float* __restrict__ mpart,
    float* __restrict__ lpart)
{
    const int kc = blockIdx.x;
    const int qc = blockIdx.y;
    const int b  = blockIdx.z;
    if (kc > (qc >> 1)) return;
    const int kv_base = kc * 256;
    const int qrel = qc * 128 - kv_base;
    int NT = ((qrel + 127) >> 6) + 1; if (NT > 4) NT = 4;

    __shared__ unsigned short Ks[2][64 * 128];
    __shared__ unsigned short Vs[2][128 * 64];

    const int tid  = threadIdx.x;
    const int wid  = tid >> 6;
    const int lane = tid & 63;
    const int c5 = lane & 31, hi = lane >> 5;
    const int q0w = qc * 128 + wid * 32;
    const int qg  = q0w + c5;
    const int pidx = b * 72 + part_offs(qc) + kc;

    const short* Kb  = kb  + (size_t)b * TLEN * HDIM;
    const short* Vtb = vtb + (size_t)b * HDIM * TLEN;

    bf16x8 qf[8];
#pragma unroll
    for (int ks = 0; ks < 8; ++ks)
        qf[ks] = *(const bf16x8*)(qb + ((size_t)b * TLEN + qg) * HDIM + ks * 16 + hi * 8);

    bf16x8 kst[4], vst[4];

#define GLOAD(kv0_)                                                          \
    {                                                                        \
        _Pragma("unroll")                                                    \
        for (int it = 0; it < 4; ++it) {                                     \
            const int o = tid * 16 + it * 4096;                              \
            const int kr = o >> 8, kcb = o & 0xF0;                           \
            kst[it] = *(const bf16x8*)((const char*)Kb +                     \
                        (size_t)((kv0_) + kr) * 256 + kcb);                  \
            const int vr = o >> 7, vcb = o & 0x70;                           \
            vst[it] = *(const bf16x8*)((const char*)Vtb +                    \
                        (size_t)vr * (TLEN * 2) + (size_t)(kv0_) * 2 + vcb); \
        }                                                                    \
    }
#define SSTORE(bi_)                                                          \
    {                                                                        \
        _Pragma("unroll")                                                    \
        for (int it = 0; it < 4; ++it) {                                     \
            const int o = tid * 16 + it * 4096;                              \
            const int kr = o >> 8, kcb = o & 0xF0;                           \
            *(bf16x8*)((char*)Ks[bi_] + kr * 256 + (kcb ^ ((kr & 7) << 4))) = kst[it]; \
            const int vr = o >> 7, vcb = o & 0x70;                           \
            *(bf16x8*)((char*)Vs[bi_] + vr * 128 + (vcb ^ ((vr & 7) << 4))) = vst[it]; \
        }                                                                    \
    }

    GLOAD(kv_base);
    SSTORE(0);
    __syncthreads();

    f32x16 oacc[4];
#pragma unroll
    for (int i = 0; i < 4; ++i)
#pragma unroll
        for (int r = 0; r < 16; ++r) oacc[i][r] = 0.f;
    float m_r = -1e30f;
    float l_r = 0.f;

#pragma unroll 1
    for (int t = 0; t < NT; ++t) {
        const int bi = t & 1;
        if (t + 1 < NT) GLOAD(kv_base + 64 * (t + 1));

        const int kv0 = kv_base + 64 * t;
        if (kv0 <= q0w + 31) {
            f32x16 s0, s1;
#pragma unroll
            for (int r = 0; r < 16; ++r) { s0[r] = 0.f; s1[r] = 0.f; }
            __builtin_amdgcn_s_setprio(1);
#pragma unroll
            for (int ks = 0; ks < 8; ++ks) {
                const int col = ks * 32 + hi * 16;
                const int off0 = c5 * 256 + (col ^ ((c5 & 7) << 4));
                const int off1 = (32 + c5) * 256 + (col ^ ((c5 & 7) << 4));
                bf16x8 a0 = *(const bf16x8*)((char*)Ks[bi] + off0);
                bf16x8 a1 = *(const bf16x8*)((char*)Ks[bi] + off1);
                s0 = __builtin_amdgcn_mfma_f32_32x32x16_bf16(a0, qf[ks], s0, 0, 0, 0);
                s1 = __builtin_amdgcn_mfma_f32_32x32x16_bf16(a1, qf[ks], s1, 0, 0, 0);
            }
            __builtin_amdgcn_s_setprio(0);

            if (kv0 + 63 > q0w) {
#pragma unroll
                for (int r = 0; r < 16; ++r) {
                    const int key0 = kv0 + (r & 3) + 8 * (r >> 2) + 4 * hi;
                    if (key0 > qg)      s0[r] = -INFINITY;
                    if (key0 + 32 > qg) s1[r] = -INFINITY;
                }
            }

            float t8[8];
#pragma unroll
            for (int i = 0; i < 8; ++i)
                t8[i] = fmaxf(fmaxf(s0[2*i], s0[2*i+1]), fmaxf(s1[2*i], s1[2*i+1]));
            float smax = fmaxf(fmaxf(fmaxf(t8[0], t8[1]), fmaxf(t8[2], t8[3])),
                               fmaxf(fmaxf(t8[4], t8[5]), fmaxf(t8[6], t8[7])));
            smax = fmaxf(smax, __shfl_xor(smax, 32));

            const bool defer = __all(smax - m_r <= 8.0f);   // T13
            const float mnew = defer ? m_r : fmaxf(m_r, smax);
            if (!defer) {
                const float alpha = __expf(m_r - mnew);
                l_r *= alpha;
#pragma unroll
                for (int hb = 0; hb < 4; ++hb) oacc[hb] = oacc[hb] * alpha;
            }
            m_r = mnew;

#pragma unroll
            for (int r = 0; r < 16; ++r) {
                s0[r] = __expf(s0[r] - mnew);
                s1[r] = __expf(s1[r] - mnew);
            }
            float a8[8];
#pragma unroll
            for (int i = 0; i < 8; ++i)
                a8[i] = (s0[2*i] + s0[2*i+1]) + (s1[2*i] + s1[2*i+1]);
            float psum = ((a8[0] + a8[1]) + (a8[2] + a8[3])) +
                         ((a8[4] + a8[5]) + (a8[6] + a8[7]));
            psum += __shfl_xor(psum, 32);
            l_r += psum;

            bf16x8 pa[4];
#pragma unroll
            for (int kb2 = 0; kb2 < 2; ++kb2) {
#pragma unroll
                for (int par = 0; par < 2; ++par) {
                    const int e = par * 8;
                    float v0, v1, v2, v3, v4, v5, v6, v7;
                    if (kb2 == 0) {
                        v0=s0[e+0]; v1=s0[e+1]; v2=s0[e+2]; v3=s0[e+3];
                        v4=s0[e+4]; v5=s0[e+5]; v6=s0[e+6]; v7=s0[e+7];
                    } else {
                        v0=s1[e+0]; v1=s1[e+1]; v2=s1[e+2]; v3=s1[e+3];
                        v4=s1[e+4]; v5=s1[e+5]; v6=s1[e+6]; v7=s1[e+7];
                    }
                    const unsigned w0 = pkbf(v0, v1), w1 = pkbf(v2, v3);
                    const unsigned w2 = pkbf(v4, v5), w3 = pkbf(v6, v7);
                    const unsigned X0 = hi ? w0 : w2;
                    const unsigned X1 = hi ? w1 : w3;
                    const unsigned R0 = (unsigned)__shfl_xor((int)X0, 32);
                    const unsigned R1 = (unsigned)__shfl_xor((int)X1, 32);
                    union { unsigned w[4]; bf16x8 v; } uu;
                    uu.w[0] = hi ? R0 : w0;  uu.w[1] = hi ? R1 : w1;
                    uu.w[2] = hi ? w2 : R0;  uu.w[3] = hi ? w3 : R1;
                    pa[kb2 * 2 + par] = uu.v;
                }
            }

            __builtin_amdgcn_s_setprio(1);
#pragma unroll
            for (int hb = 0; hb < 4; ++hb) {
                const int row = hb * 32 + c5;
#pragma unroll
                for (int ks = 0; ks < 4; ++ks) {
                    const int off = row * 128 + ((ks * 32 + hi * 16) ^ ((row & 7) << 4));
                    bf16x8 va = *(const bf16x8*)((char*)Vs[bi] + off);
                    oacc[hb] = __builtin_amdgcn_mfma_f32_32x32x16_bf16(va, pa[ks], oacc[hb], 0, 0, 0);
                }
            }
            __builtin_amdgcn_s_setprio(0);
        }

        if (t + 1 < NT) {
            SSTORE(bi ^ 1);
            __syncthreads();
        }
    }

    // ---- epilogue: transpose O via LDS, store partials bf16 ----
    __syncthreads();
    char* sl = (char*)Ks + wid * 8192;
#pragma unroll
    for (int hb = 0; hb < 4; ++hb)
#pragma unroll
        for (int rq = 0; rq < 4; ++rq) {
            u16x4 o4;
            o4[0] = f2bf(oacc[hb][rq * 4 + 0]);
            o4[1] = f2bf(oacc[hb][rq * 4 + 1]);
            o4[2] = f2bf(oacc[hb][rq * 4 + 2]);
            o4[3] = f2bf(oacc[hb][rq * 4 + 3]);
            const int off = c5 * 256 + ((hb * 64 + rq * 16 + hi * 8) ^ ((c5 & 7) << 4));
            *(u16x4*)(sl + off) = o4;
        }
    asm volatile("s_waitcnt lgkmcnt(0)" ::: "memory");
    __builtin_amdgcn_sched_barrier(0);

    const int qr = lane >> 1, hf = lane & 1;
    unsigned short* Og = Opart + (size_t)pidx * 128 * 128 +
                         (size_t)(wid * 32 + qr) * 128 + hf * 64;
#pragma unroll
    for (int i = 0; i < 8; ++i) {
        const int off = qr * 256 + ((hf * 128 + i * 16) ^ ((qr & 7) << 4));
        *(u16x8*)(Og + i * 8) = *(const u16x8*)(sl + off);
    }
    if (hi == 0) {
        mpart[(size_t)pidx * 128 + wid * 32 + c5] = m_r;
        lpart[(size_t)pidx * 128 + wid * 32 + c5] = l_r;
    }
#undef GLOAD
#undef SSTORE
}

// ---------------------------------------------------------------------------
// Kernel 2b: combine partials (unchanged).
// ---------------------------------------------------------------------------
__global__ __launch_bounds__(256) void attn_combine(
    const unsigned short* __restrict__ Opart, const float* __restrict__ mpart,
    const float* __restrict__ lpart, float* __restrict__ out)
{
    const int qc = blockIdx.x;
    const int b  = blockIdx.y;
    const int n  = (qc >> 1) + 1;
    const int base = b * 72 + part_offs(qc);
    const int t   = threadIdx.x;
    const int row = t >> 1;
    const int d0  = (t & 1) * 64;

    float M = -INFINITY;
    for (int p = 0; p < n; ++p)
        M = fmaxf(M, mpart[(size_t)(base + p) * 128 + row]);
    float L = 0.f;
    for (int p = 0; p < n; ++p)
        L += __expf(mpart[(size_t)(base + p) * 128 + row] - M) *
             lpart[(size_t)(base + p) * 128 + row];

    float acc[64];
#pragma unroll
    for (int i = 0; i < 64; ++i) acc[i] = 0.f;

    for (int p = 0; p < n; ++p) {
        const float w = __expf(mpart[(size_t)(base + p) * 128 + row] - M);
        const bf16x8* src = (const bf16x8*)(Opart +
            ((size_t)(base + p) * 128 + row) * 128 + d0);
#pragma unroll
        for (int j = 0; j < 8; ++j) {
            bf16x8 v = src[j];
#pragma unroll
            for (int e = 0; e < 8; ++e) {
                union { unsigned u; float f; } xx;
                xx.u = ((unsigned)(unsigned short)v[e]) << 16;
                acc[j * 8 + e] += w * xx.f;
            }
        }
    }

    const float invL = 1.f / L;
    float4* dst = (float4*)(out + ((size_t)(b * TLEN + qc * 128 + row)) * 128 + d0);
#pragma unroll
    for (int i = 0; i < 16; ++i)
        dst[i] = make_float4(acc[4*i] * invL, acc[4*i+1] * invL,
                             acc[4*i+2] * invL, acc[4*i+3] * invL);
}

extern "C" void kernel_launch(void* const* d_in, const int* in_sizes, int n_in,
                              void* d_out, int out_size, void* d_ws, size_t ws_size,
                              hipStream_t stream)
{
    const float* x  = (const float*)d_in[0];
    const float* Wq = (const float*)d_in[1];
    const float* Wk = (const float*)d_in[2];
    const float* Wv = (const float*)d_in[3];
    float* outp = (float*)d_out;

    const size_t per = (size_t)BATCH * TLEN * HDIM;      // 4,194,304
    unsigned short* qb  = (unsigned short*)d_ws;
    unsigned short* kb  = qb + per;
    unsigned short* vtb = kb + per;
    unsigned short* wtb = vtb + per;                     // 384*1024 bf16
    unsigned short* Opart = wtb + 384 * 1024;            // 1152*128*128 bf16
    float* mpart = (float*)(Opart + (size_t)1152 * 128 * 128);
    float* lpart = mpart + (size_t)1152 * 128;

    dim3 gw(512, 3);
    pack_w<<<gw, 256, 0, stream>>>(Wq, Wk, Wv, wtb);

    qkv_fused<<<512, 512, 0, stream>>>(x, wtb, qb, kb, vtb);

    dim3 g2(8, 16, BATCH);
    attn_partial<<<g2, 256, 0, stream>>>((const short*)qb, (const short*)kb,
                                         (const short*)vtb, Opart, mpart, lpart);

    dim3 g3(16, BATCH);
    attn_combine<<<g3, 256, 0, stream>>>(Opart, mpart, lpart, outp);
}

// Round 17
// 112.766 us; speedup vs baseline: 1.7591x; 1.1529x over previous
//
#include <hip/hip_runtime.h>
#include <hip/hip_bf16.h>

#define BATCH 16
#define TLEN 2048
#define CDIM 1024
#define HDIM 128

typedef __attribute__((ext_vector_type(8))) short bf16x8;
typedef __attribute__((ext_vector_type(4))) float f32x4;
typedef __attribute__((ext_vector_type(16))) float f32x16;
typedef __attribute__((ext_vector_type(4))) unsigned short u16x4;
typedef __attribute__((ext_vector_type(8))) unsigned short u16x8;

static __device__ __forceinline__ unsigned short f2bf(float f) {
    __hip_bfloat16 h = __float2bfloat16(f);
    return *(unsigned short*)&h;
}
static __device__ __forceinline__ unsigned pkbf(float a, float b) {
    return (unsigned)f2bf(a) | ((unsigned)f2bf(b) << 16);
}
// KV-chunk = 512 keys.  partials per (b,qc) prefix: sum_{j<qc} (j/4 + 1)
static __device__ __forceinline__ int part_offs(int qc) {
    const int g = qc >> 2;
    return qc + 2 * g * (g - 1) + (qc & 3) * g;
}

typedef const __attribute__((address_space(1))) unsigned int* gas_t;
typedef __attribute__((address_space(3))) unsigned int* las_t;
static __device__ __forceinline__ void gl_lds16(const void* g, void* l) {
    __builtin_amdgcn_global_load_lds((gas_t)g, (las_t)l, 16, 0, 0);
}

// raw barrier pinned against compiler reordering (rule 18 / m201 pattern)
static __device__ __forceinline__ void hard_barrier() {
    __builtin_amdgcn_sched_barrier(0);
    __builtin_amdgcn_s_barrier();
    __builtin_amdgcn_sched_barrier(0);
}

// ---------------------------------------------------------------------------
// Prep: pack Wq|Wk|Wv into transposed bf16  wtb[(which*128+n)*1024 + k].
// ---------------------------------------------------------------------------
__global__ __launch_bounds__(256) void pack_w(
    const float* __restrict__ Wq, const float* __restrict__ Wk,
    const float* __restrict__ Wv, unsigned short* __restrict__ wtb)
{
    const int which = blockIdx.y;
    const float* W = (which == 0) ? Wq : (which == 1) ? Wk : Wv;
    const int n = blockIdx.x >> 2;
    const int k = (blockIdx.x & 3) * 256 + threadIdx.x;
    wtb[((size_t)which * 128 + n) * 1024 + k] = f2bf(W[(size_t)k * 128 + n]);
}

// ---------------------------------------------------------------------------
// Kernel 1: FUSED QKV projection (FROZEN r16 — empirical floor ~78us).
// BM=128, BN=192, BK=64, 512 thr / 8 waves, grid 512, XCD-paired.
// ---------------------------------------------------------------------------
__global__ __launch_bounds__(512, 4) void qkv_fused(
    const float* __restrict__ x, const unsigned short* __restrict__ wtb,
    unsigned short* __restrict__ qb, unsigned short* __restrict__ kb,
    unsigned short* __restrict__ vtb)
{
    __shared__ __align__(16) unsigned short Ab[2][128 * 64];   // 2 x 16KB [m][k] bf16
    __shared__ __align__(16) unsigned short Bb[2][192 * 64];   // 2 x 24KB [n][k] bf16

    const int xcd = blockIdx.x & 7, s = blockIdx.x >> 3;
    const int m0 = (xcd * 32 + (s >> 1)) * 128;
    const int nh = s & 1;

    const int tid  = threadIdx.x;
    const int lane = tid & 63, wid = tid >> 6;
    const int wm = wid >> 2, wn = wid & 3;
    const int c = lane & 15, g = lane >> 4;

    const int arow = tid >> 2, aq = tid & 3;
    const float* xsrc = x + (size_t)(m0 + arow) * CDIM + aq * 16;

    f32x4 acc[4][3];
#pragma unroll
    for (int i = 0; i < 4; ++i)
#pragma unroll
        for (int j = 0; j < 3; ++j) acc[i][j] = (f32x4){0.f, 0.f, 0.f, 0.f};

    float4 As0, As1, As2, As3;

#define AISSUE(k0_)                                                          \
    { const float* s_ = xsrc + (k0_);                                        \
      As0 = *(const float4*)(s_);      As1 = *(const float4*)(s_ + 4);       \
      As2 = *(const float4*)(s_ + 8);  As3 = *(const float4*)(s_ + 12); }

#define AWRITE(bi_)                                                          \
    { u16x8 t0_, t1_;                                                        \
      t0_[0]=f2bf(As0.x); t0_[1]=f2bf(As0.y); t0_[2]=f2bf(As0.z); t0_[3]=f2bf(As0.w); \
      t0_[4]=f2bf(As1.x); t0_[5]=f2bf(As1.y); t0_[6]=f2bf(As1.z); t0_[7]=f2bf(As1.w); \
      t1_[0]=f2bf(As2.x); t1_[1]=f2bf(As2.y); t1_[2]=f2bf(As2.z); t1_[3]=f2bf(As2.w); \
      t1_[4]=f2bf(As3.x); t1_[5]=f2bf(As3.y); t1_[6]=f2bf(As3.z); t1_[7]=f2bf(As3.w); \
      char* ba_ = (char*)Ab[bi_] + arow * 128;                               \
      *(u16x8*)(ba_ + ((aq * 32 +  0) ^ ((arow & 7) << 4))) = t0_;           \
      *(u16x8*)(ba_ + ((aq * 32 + 16) ^ ((arow & 7) << 4))) = t1_; }

#define BISSUE(k0_, bi_)                                                     \
    { _Pragma("unroll")                                                      \
      for (int i_ = 0; i_ < 3; ++i_) {                                       \
          const int seg_ = wid * 3 + i_;                                     \
          const int row_ = seg_ * 8 + (lane >> 3);                           \
          const int gr_  = (lane & 7) ^ (row_ & 7);                          \
          gl_lds16(wtb + (size_t)(nh * 192 + row_) * 1024 + (k0_) + gr_ * 8, \
                   (char*)Bb[bi_] + seg_ * 1024);                            \
      } }

    AISSUE(0);
    BISSUE(0, 0);
    asm volatile("s_waitcnt vmcnt(3)" ::: "memory");
    AWRITE(0);
    asm volatile("s_waitcnt vmcnt(0) lgkmcnt(0)" ::: "memory");
    hard_barrier();

#pragma unroll 1
    for (int kt = 0; kt < 16; ++kt) {
        const int cur = kt & 1;
        if (kt < 15) {
            AISSUE((kt + 1) * 64);
            BISSUE((kt + 1) * 64, cur ^ 1);
        }

#pragma unroll
        for (int ks = 0; ks < 2; ++ks) {
            bf16x8 af[4], bf[3];
#pragma unroll
            for (int mf = 0; mf < 4; ++mf) {
                const int rm = wm * 64 + mf * 16 + c;
                af[mf] = *(const bf16x8*)((char*)Ab[cur] + rm * 128 +
                                          ((ks * 64 + g * 16) ^ ((rm & 7) << 4)));
            }
#pragma unroll
            for (int nf = 0; nf < 3; ++nf) {
                const int rn = wn * 48 + nf * 16 + c;
                bf[nf] = *(const bf16x8*)((char*)Bb[cur] + rn * 128 +
                                          ((ks * 64 + g * 16) ^ ((rn & 7) << 4)));
            }
            __builtin_amdgcn_s_setprio(1);
#pragma unroll
            for (int mf = 0; mf < 4; ++mf)
#pragma unroll
                for (int nf = 0; nf < 3; ++nf)
                    acc[mf][nf] = __builtin_amdgcn_mfma_f32_16x16x32_bf16(
                        af[mf], bf[nf], acc[mf][nf], 0, 0, 0);
            __builtin_amdgcn_s_setprio(0);
        }

        if (kt < 15) {
            asm volatile("s_waitcnt vmcnt(3)" ::: "memory");
            AWRITE(cur ^ 1);
            asm volatile("s_waitcnt vmcnt(0) lgkmcnt(0)" ::: "memory");
            hard_barrier();
        }
    }

#pragma unroll
    for (int mf = 0; mf < 4; ++mf) {
#pragma unroll
        for (int nf = 0; nf < 3; ++nf) {
            const int col0 = nh * 192 + wn * 48 + nf * 16;
            const int nt = col0 >> 7;
            const int nc = (col0 & 127) + c;
            const int m = m0 + wm * 64 + mf * 16 + g * 4;
            if (nt == 0) {
#pragma unroll
                for (int r = 0; r < 4; ++r)
                    qb[(size_t)(m + r) * HDIM + nc] = f2bf(acc[mf][nf][r] * 0.03125f);
            } else if (nt == 1) {
#pragma unroll
                for (int r = 0; r < 4; ++r)
                    kb[(size_t)(m + r) * HDIM + nc] = f2bf(acc[mf][nf][r]);
            } else {
                const int b = m >> 11, tl = m & (TLEN - 1);
                u16x4 o;
                o[0] = f2bf(acc[mf][nf][0]); o[1] = f2bf(acc[mf][nf][1]);
                o[2] = f2bf(acc[mf][nf][2]); o[3] = f2bf(acc[mf][nf][3]);
                *(u16x4*)(vtb + ((size_t)b * HDIM + nc) * TLEN + tl) = o;
            }
        }
    }
#undef AISSUE
#undef AWRITE
#undef BISSUE
}

// ---------------------------------------------------------------------------
// Kernel 2a: flash-attention partials, KV-chunk = 512 (was 256).
// Task = (b, qc [128 q rows], kc [512 keys]), active iff kc <= qc/4.
// Up to 8 KV tiles of 64 per block (2x amortization of q-load/epilogue).
// Same 32x32 swapped-operand math as rounds 7-16.
// ---------------------------------------------------------------------------
__global__ __launch_bounds__(256, 2) void attn_partial(
    const short* __restrict__ qb, const short* __restrict__ kb,
    const short* __restrict__ vtb,
    unsigned short* __restrict__ Opart, float* __restrict__ mpart,
    float* __restrict__ lpart)
{
    const int kc = blockIdx.x;          // 0..3   (512-key chunk)
    const int qc = blockIdx.y;          // 0..15  (128-row chunk)
    const int b  = blockIdx.z;
    if (kc > (qc >> 2)) return;
    const int kv_base = kc * 512;
    const int qrel = qc * 128 - kv_base;             // >= 0 for active blocks
    int NT = (qrel >> 6) + 2; if (NT > 8) NT = 8;

    __shared__ unsigned short Ks[2][64 * 128];
    __shared__ unsigned short Vs[2][128 * 64];

    const int tid  = threadIdx.x;
    const int wid  = tid >> 6;
    const int lane = tid & 63;
    const int c5 = lane & 31, hi = lane >> 5;
    const int q0w = qc * 128 + wid * 32;
    const int qg  = q0w + c5;
    const int pidx = b * 40 + part_offs(qc) + kc;

    const short* Kb  = kb  + (size_t)b * TLEN * HDIM;
    const short* Vtb = vtb + (size_t)b * HDIM * TLEN;

    bf16x8 qf[8];
#pragma unroll
    for (int ks = 0; ks < 8; ++ks)
        qf[ks] = *(const bf16x8*)(qb + ((size_t)b * TLEN + qg) * HDIM + ks * 16 + hi * 8);

    bf16x8 kst[4], vst[4];

#define GLOAD(kv0_)                                                          \
    {                                                                        \
        _Pragma("unroll")                                                    \
        for (int it = 0; it < 4; ++it) {                                     \
            const int o = tid * 16 + it * 4096;                              \
            const int kr = o >> 8, kcb = o & 0xF0;                           \
            kst[it] = *(const bf16x8*)((const char*)Kb +                     \
                        (size_t)((kv0_) + kr) * 256 + kcb);                  \
            const int vr = o >> 7, vcb = o & 0x70;                           \
            vst[it] = *(const bf16x8*)((const char*)Vtb +                    \
                        (size_t)vr * (TLEN * 2) + (size_t)(kv0_) * 2 + vcb); \
        }                                                                    \
    }
#define SSTORE(bi_)                                                          \
    {                                                                        \
        _Pragma("unroll")                                                    \
        for (int it = 0; it < 4; ++it) {                                     \
            const int o = tid * 16 + it * 4096;                              \
            const int kr = o >> 8, kcb = o & 0xF0;                           \
            *(bf16x8*)((char*)Ks[bi_] + kr * 256 + (kcb ^ ((kr & 7) << 4))) = kst[it]; \
            const int vr = o >> 7, vcb = o & 0x70;                           \
            *(bf16x8*)((char*)Vs[bi_] + vr * 128 + (vcb ^ ((vr & 7) << 4))) = vst[it]; \
        }                                                                    \
    }

    GLOAD(kv_base);
    SSTORE(0);
    __syncthreads();

    f32x16 oacc[4];
#pragma unroll
    for (int i = 0; i < 4; ++i)
#pragma unroll
        for (int r = 0; r < 16; ++r) oacc[i][r] = 0.f;
    float m_r = -1e30f;
    float l_r = 0.f;

#pragma unroll 1
    for (int t = 0; t < NT; ++t) {
        const int bi = t & 1;
        if (t + 1 < NT) GLOAD(kv_base + 64 * (t + 1));

        const int kv0 = kv_base + 64 * t;
        if (kv0 <= q0w + 31) {
            f32x16 s0, s1;
#pragma unroll
            for (int r = 0; r < 16; ++r) { s0[r] = 0.f; s1[r] = 0.f; }
            __builtin_amdgcn_s_setprio(1);
#pragma unroll
            for (int ks = 0; ks < 8; ++ks) {
                const int col = ks * 32 + hi * 16;
                const int off0 = c5 * 256 + (col ^ ((c5 & 7) << 4));
                const int off1 = (32 + c5) * 256 + (col ^ ((c5 & 7) << 4));
                bf16x8 a0 = *(const bf16x8*)((char*)Ks[bi] + off0);
                bf16x8 a1 = *(const bf16x8*)((char*)Ks[bi] + off1);
                s0 = __builtin_amdgcn_mfma_f32_32x32x16_bf16(a0, qf[ks], s0, 0, 0, 0);
                s1 = __builtin_amdgcn_mfma_f32_32x32x16_bf16(a1, qf[ks], s1, 0, 0, 0);
            }
            __builtin_amdgcn_s_setprio(0);

            if (kv0 + 63 > q0w) {
#pragma unroll
                for (int r = 0; r < 16; ++r) {
                    const int key0 = kv0 + (r & 3) + 8 * (r >> 2) + 4 * hi;
                    if (key0 > qg)      s0[r] = -INFINITY;
                    if (key0 + 32 > qg) s1[r] = -INFINITY;
                }
            }

            float t8[8];
#pragma unroll
            for (int i = 0; i < 8; ++i)
                t8[i] = fmaxf(fmaxf(s0[2*i], s0[2*i+1]), fmaxf(s1[2*i], s1[2*i+1]));
            float smax = fmaxf(fmaxf(fmaxf(t8[0], t8[1]), fmaxf(t8[2], t8[3])),
                               fmaxf(fmaxf(t8[4], t8[5]), fmaxf(t8[6], t8[7])));
            smax = fmaxf(smax, __shfl_xor(smax, 32));

            const bool defer = __all(smax - m_r <= 8.0f);   // T13
            const float mnew = defer ? m_r : fmaxf(m_r, smax);
            if (!defer) {
                const float alpha = __expf(m_r - mnew);
                l_r *= alpha;
#pragma unroll
                for (int hb = 0; hb < 4; ++hb) oacc[hb] = oacc[hb] * alpha;
            }
            m_r = mnew;

#pragma unroll
            for (int r = 0; r < 16; ++r) {
                s0[r] = __expf(s0[r] - mnew);
                s1[r] = __expf(s1[r] - mnew);
            }
            float a8[8];
#pragma unroll
            for (int i = 0; i < 8; ++i)
                a8[i] = (s0[2*i] + s0[2*i+1]) + (s1[2*i] + s1[2*i+1]);
            float psum = ((a8[0] + a8[1]) + (a8[2] + a8[3])) +
                         ((a8[4] + a8[5]) + (a8[6] + a8[7]));
            psum += __shfl_xor(psum, 32);
            l_r += psum;

            bf16x8 pa[4];
#pragma unroll
            for (int kb2 = 0; kb2 < 2; ++kb2) {
#pragma unroll
                for (int par = 0; par < 2; ++par) {
                    const int e = par * 8;
                    float v0, v1, v2, v3, v4, v5, v6, v7;
                    if (kb2 == 0) {
                        v0=s0[e+0]; v1=s0[e+1]; v2=s0[e+2]; v3=s0[e+3];
                        v4=s0[e+4]; v5=s0[e+5]; v6=s0[e+6]; v7=s0[e+7];
                    } else {
                        v0=s1[e+0]; v1=s1[e+1]; v2=s1[e+2]; v3=s1[e+3];
                        v4=s1[e+4]; v5=s1[e+5]; v6=s1[e+6]; v7=s1[e+7];
                    }
                    const unsigned w0 = pkbf(v0, v1), w1 = pkbf(v2, v3);
                    const unsigned w2 = pkbf(v4, v5), w3 = pkbf(v6, v7);
                    const unsigned X0 = hi ? w0 : w2;
                    const unsigned X1 = hi ? w1 : w3;
                    const unsigned R0 = (unsigned)__shfl_xor((int)X0, 32);
                    const unsigned R1 = (unsigned)__shfl_xor((int)X1, 32);
                    union { unsigned w[4]; bf16x8 v; } uu;
                    uu.w[0] = hi ? R0 : w0;  uu.w[1] = hi ? R1 : w1;
                    uu.w[2] = hi ? w2 : R0;  uu.w[3] = hi ? w3 : R1;
                    pa[kb2 * 2 + par] = uu.v;
                }
            }

            __builtin_amdgcn_s_setprio(1);
#pragma unroll
            for (int hb = 0; hb < 4; ++hb) {
                const int row = hb * 32 + c5;
#pragma unroll
                for (int ks = 0; ks < 4; ++ks) {
                    const int off = row * 128 + ((ks * 32 + hi * 16) ^ ((row & 7) << 4));
                    bf16x8 va = *(const bf16x8*)((char*)Vs[bi] + off);
                    oacc[hb] = __builtin_amdgcn_mfma_f32_32x32x16_bf16(va, pa[ks], oacc[hb], 0, 0, 0);
                }
            }
            __builtin_amdgcn_s_setprio(0);
        }

        if (t + 1 < NT) {
            SSTORE(bi ^ 1);
            __syncthreads();
        }
    }

    // ---- epilogue: transpose O via LDS, store partials bf16 ----
    __syncthreads();
    char* sl = (char*)Ks + wid * 8192;
#pragma unroll
    for (int hb = 0; hb < 4; ++hb)
#pragma unroll
        for (int rq = 0; rq < 4; ++rq) {
            u16x4 o4;
            o4[0] = f2bf(oacc[hb][rq * 4 + 0]);
            o4[1] = f2bf(oacc[hb][rq * 4 + 1]);
            o4[2] = f2bf(oacc[hb][rq * 4 + 2]);
            o4[3] = f2bf(oacc[hb][rq * 4 + 3]);
            const int off = c5 * 256 + ((hb * 64 + rq * 16 + hi * 8) ^ ((c5 & 7) << 4));
            *(u16x4*)(sl + off) = o4;
        }
    asm volatile("s_waitcnt lgkmcnt(0)" ::: "memory");
    __builtin_amdgcn_sched_barrier(0);

    const int qr = lane >> 1, hf = lane & 1;
    unsigned short* Og = Opart + (size_t)pidx * 128 * 128 +
                         (size_t)(wid * 32 + qr) * 128 + hf * 64;
#pragma unroll
    for (int i = 0; i < 8; ++i) {
        const int off = qr * 256 + ((hf * 128 + i * 16) ^ ((qr & 7) << 4));
        *(u16x8*)(Og + i * 8) = *(const u16x8*)(sl + off);
    }
    if (hi == 0) {
        mpart[(size_t)pidx * 128 + wid * 32 + c5] = m_r;
        lpart[(size_t)pidx * 128 + wid * 32 + c5] = l_r;
    }
#undef GLOAD
#undef SSTORE
}

// ---------------------------------------------------------------------------
// Kernel 2b: combine partials (n <= 4 now; m/l cached in registers).
// ---------------------------------------------------------------------------
__global__ __launch_bounds__(256) void attn_combine(
    const unsigned short* __restrict__ Opart, const float* __restrict__ mpart,
    const float* __restrict__ lpart, float* __restrict__ out)
{
    const int qc = blockIdx.x;
    const int b  = blockIdx.y;
    const int n  = (qc >> 2) + 1;
    const int base = b * 40 + part_offs(qc);
    const int t   = threadIdx.x;
    const int row = t >> 1;
    const int d0  = (t & 1) * 64;

    float mv[4], lv[4];
#pragma unroll
    for (int p = 0; p < 4; ++p) {
        mv[p] = (p < n) ? mpart[(size_t)(base + p) * 128 + row] : -INFINITY;
        lv[p] = (p < n) ? lpart[(size_t)(base + p) * 128 + row] : 0.f;
    }
    float M = fmaxf(fmaxf(mv[0], mv[1]), fmaxf(mv[2], mv[3]));
    float L = 0.f;
    float wv[4];
#pragma unroll
    for (int p = 0; p < 4; ++p) {
        wv[p] = (p < n) ? __expf(mv[p] - M) : 0.f;
        L += wv[p] * lv[p];
    }

    float acc[64];
#pragma unroll
    for (int i = 0; i < 64; ++i) acc[i] = 0.f;

    for (int p = 0; p < n; ++p) {
        const float w = wv[p];
        const bf16x8* src = (const bf16x8*)(Opart +
            ((size_t)(base + p) * 128 + row) * 128 + d0);
#pragma unroll
        for (int j = 0; j < 8; ++j) {
            bf16x8 v = src[j];
#pragma unroll
            for (int e = 0; e < 8; ++e) {
                union { unsigned u; float f; } xx;
                xx.u = ((unsigned)(unsigned short)v[e]) << 16;
                acc[j * 8 + e] += w * xx.f;
            }
        }
    }

    const float invL = 1.f / L;
    float4* dst = (float4*)(out + ((size_t)(b * TLEN + qc * 128 + row)) * 128 + d0);
#pragma unroll
    for (int i = 0; i < 16; ++i)
        dst[i] = make_float4(acc[4*i] * invL, acc[4*i+1] * invL,
                             acc[4*i+2] * invL, acc[4*i+3] * invL);
}

extern "C" void kernel_launch(void* const* d_in, const int* in_sizes, int n_in,
                              void* d_out, int out_size, void* d_ws, size_t ws_size,
                              hipStream_t stream)
{
    const float* x  = (const float*)d_in[0];
    const float* Wq = (const float*)d_in[1];
    const float* Wk = (const float*)d_in[2];
    const float* Wv = (const float*)d_in[3];
    float* outp = (float*)d_out;

    const size_t per = (size_t)BATCH * TLEN * HDIM;      // 4,194,304
    unsigned short* qb  = (unsigned short*)d_ws;
    unsigned short* kb  = qb + per;
    unsigned short* vtb = kb + per;
    unsigned short* wtb = vtb + per;                     // 384*1024 bf16
    unsigned short* Opart = wtb + 384 * 1024;            // 640*128*128 bf16
    float* mpart = (float*)(Opart + (size_t)640 * 128 * 128);
    float* lpart = mpart + (size_t)640 * 128;

    dim3 gw(512, 3);
    pack_w<<<gw, 256, 0, stream>>>(Wq, Wk, Wv, wtb);

    qkv_fused<<<512, 512, 0, stream>>>(x, wtb, qb, kb, vtb);

    dim3 g2(4, 16, BATCH);
    attn_partial<<<g2, 256, 0, stream>>>((const short*)qb, (const short*)kb,
                                         (const short*)vtb, Opart, mpart, lpart);

    dim3 g3(16, BATCH);
    attn_combine<<<g3, 256, 0, stream>>>(Opart, mpart, lpart, outp);
}